// Round 1
// baseline (647.787 us; speedup 1.0000x reference)
//
#include <hip/hip_runtime.h>
#include <math.h>

#define NN 50000
#define EE 1250000
#define GG 16
#define NCLS 5

constexpr size_t AL(size_t x){ return (x + 255) & ~size_t(255); }
constexpr size_t OFF_DEG    = 0;
constexpr size_t OFF_ROWPTR = OFF_DEG + AL((size_t)NN*4);
constexpr size_t OFF_CURSOR = OFF_ROWPTR + AL((size_t)(NN+1)*4);
constexpr size_t OFF_CSR    = OFF_CURSOR + AL((size_t)NN*4);
constexpr size_t OFF_SE     = OFF_CSR + AL((size_t)EE*8);
constexpr size_t OFF_SSRC   = OFF_SE + AL((size_t)EE*5*4);
constexpr size_t OFF_SDST   = OFF_SSRC + AL((size_t)NN*2*4);
constexpr size_t OFF_BUFH   = OFF_SDST + AL((size_t)NN*2*4);
constexpr size_t OFF_BUFO   = OFF_BUFH + AL((size_t)NN*64*4);
constexpr size_t OFF_WEFF   = OFF_BUFO + AL((size_t)NN*64*4);
constexpr size_t OFF_POOL   = OFF_WEFF + AL(80*4);
// pool = GG*32 floats, then cnt = GG floats (contiguous, zeroed together)

__device__ __forceinline__ float leaky(float x){ return x > 0.f ? x : 0.2f*x; }

// ---------------- CSR build ----------------
__global__ void deg_kernel(const int* __restrict__ dst, int* __restrict__ deg, int nE){
    int e = blockIdx.x*256 + threadIdx.x;
    if (e < nE) atomicAdd(&deg[dst[e]], 1);
}

__global__ void scan_kernel(const int* __restrict__ deg, int* __restrict__ rowptr,
                            int* __restrict__ cursor, int nN){
    __shared__ int s[1024];
    int tid = threadIdx.x;
    int running = 0;
    for (int base = 0; base < nN; base += 1024){
        int v = (base + tid < nN) ? deg[base + tid] : 0;
        s[tid] = v;
        __syncthreads();
        for (int off = 1; off < 1024; off <<= 1){
            int t = (tid >= off) ? s[tid - off] : 0;
            __syncthreads();
            s[tid] += t;
            __syncthreads();
        }
        int inc = s[tid];
        int tot = s[1023];
        if (base + tid < nN){
            rowptr[base + tid] = running + inc - v;
            cursor[base + tid] = running + inc - v;
        }
        running += tot;
        __syncthreads();
    }
    if (tid == 0) rowptr[nN] = running;
}

__global__ void fill_kernel(const int* __restrict__ src, const int* __restrict__ dst,
                            int* __restrict__ cursor, int2* __restrict__ csr, int nE){
    int e = blockIdx.x*256 + threadIdx.x;
    if (e < nE){
        int d = dst[e];
        int pos = atomicAdd(&cursor[d], 1);
        csr[pos] = make_int2(src[e], e);
    }
}

// ---------------- edge score precompute ----------------
// weff[j][d] , j: 0=L1h0 1=L1h1 2=L2h0 3=L2h1 4=L3h0
__global__ void weff_kernel(const float* __restrict__ We1, const float* __restrict__ ae1,
                            const float* __restrict__ We2, const float* __restrict__ ae2,
                            const float* __restrict__ We3, const float* __restrict__ ae3,
                            float* __restrict__ weff){
    int t = threadIdx.x;
    if (t >= 80) return;
    int j = t >> 4, d = t & 15;
    const float* We; const float* ae; int hc, h;
    if (j == 0){ We = We1; ae = ae1; hc = 64; h = 0; }
    else if (j == 1){ We = We1; ae = ae1; hc = 64; h = 1; }
    else if (j == 2){ We = We2; ae = ae2; hc = 64; h = 0; }
    else if (j == 3){ We = We2; ae = ae2; hc = 64; h = 1; }
    else { We = We3; ae = ae3; hc = 32; h = 0; }
    float s = 0.f;
    for (int c = 0; c < 32; ++c) s += We[d*hc + h*32 + c] * ae[h*32 + c];
    weff[j*16 + d] = s;
}

// se (SoA, 5 arrays of E) in CSR order: se[j*E + p] = eattr[csr[p].e] . weff[j]
__global__ void se_kernel(const int2* __restrict__ csr, const float* __restrict__ eattr,
                          const float* __restrict__ weff, float* __restrict__ se, int nE){
    __shared__ float w[80];
    int tid = threadIdx.x;
    if (tid < 80) w[tid] = weff[tid];
    __syncthreads();
    int p = blockIdx.x*256 + tid;
    if (p >= nE) return;
    int e = csr[p].y;
    const float4* row = (const float4*)(eattr + (size_t)e*16);
    float4 a0 = row[0], a1 = row[1], a2 = row[2], a3 = row[3];
    float a[16] = {a0.x,a0.y,a0.z,a0.w, a1.x,a1.y,a1.z,a1.w,
                   a2.x,a2.y,a2.z,a2.w, a3.x,a3.y,a3.z,a3.w};
    #pragma unroll
    for (int j = 0; j < 5; ++j){
        float s = 0.f;
        #pragma unroll
        for (int d = 0; d < 16; ++d) s += a[d]*w[j*16+d];
        se[(size_t)j*nE + p] = s;
    }
}

// ---------------- node transform: h = in @ W ; s_src/s_dst fused ----------------
template<int OUTC>
__global__ void transform_kernel(const float* __restrict__ in, const float* __restrict__ W,
                                 const float* __restrict__ asrc, const float* __restrict__ adst,
                                 float* __restrict__ hout, float* __restrict__ ssrc,
                                 float* __restrict__ sdst, int nN){
    constexpr int R = 256/OUTC;
    __shared__ float Ws[64*OUTC];
    __shared__ float ins[R*64];
    int tid = threadIdx.x;
    for (int i = tid; i < 64*OUTC; i += 256) Ws[i] = W[i];
    int base = blockIdx.x * R;
    for (int i = tid; i < R*64; i += 256){
        int n = base + i/64;
        ins[i] = (n < nN) ? in[(size_t)n*64 + (i & 63)] : 0.f;
    }
    __syncthreads();
    int r = tid / OUTC, c = tid % OUTC;
    int n = base + r;
    float acc = 0.f;
    #pragma unroll
    for (int d = 0; d < 64; ++d) acc += ins[r*64 + d] * Ws[d*OUTC + c];
    float ps = acc * asrc[c];
    float pd = acc * adst[c];
    #pragma unroll
    for (int m = 1; m <= 16; m <<= 1){ ps += __shfl_xor(ps, m); pd += __shfl_xor(pd, m); }
    if (n < nN){
        hout[(size_t)n*OUTC + c] = acc;
        constexpr int HEADS = OUTC/32;
        if ((c & 31) == 0){
            int h = c >> 5;
            ssrc[n*HEADS + h] = ps;
            sdst[n*HEADS + h] = pd;
        }
    }
}

// ---------------- per-dst aggregation (one wave per node) ----------------
template<int OUTC>
__global__ void agg_kernel(const int* __restrict__ rowptr, const int2* __restrict__ csr,
                           const float* __restrict__ se0, const float* __restrict__ se1,
                           const float* __restrict__ ssrc, const float* __restrict__ sdst,
                           const float* __restrict__ hbuf, const float* __restrict__ bias,
                           float* __restrict__ outbuf, int nN){
    constexpr int HEADS = OUTC/32;
    int wid = threadIdx.x >> 6;
    int lane = threadIdx.x & 63;
    int n = blockIdx.x*4 + wid;
    if (n >= nN) return;
    int row_start = rowptr[n], row_end = rowptr[n+1];
    int degn = row_end - row_start;
    float sd0 = sdst[n*HEADS + 0];
    float sd1 = (HEADS == 2) ? sdst[n*HEADS + 1] : 0.f;

    // scan 1: max logit per head + raw s_e sums (for self-loop mean attr)
    float m0 = -INFINITY, m1 = -INFINITY, ss0 = 0.f, ss1 = 0.f;
    for (int p = row_start + lane; p < row_end; p += 64){
        int s = csr[p].x;
        float e0 = se0[p];
        float l0 = leaky(ssrc[s*HEADS + 0] + sd0 + e0);
        m0 = fmaxf(m0, l0); ss0 += e0;
        if (HEADS == 2){
            float e1 = se1[p];
            float l1 = leaky(ssrc[s*HEADS + 1] + sd1 + e1);
            m1 = fmaxf(m1, l1); ss1 += e1;
        }
    }
    #pragma unroll
    for (int mm = 1; mm < 64; mm <<= 1){
        m0 = fmaxf(m0, __shfl_xor(m0, mm)); ss0 += __shfl_xor(ss0, mm);
        if (HEADS == 2){ m1 = fmaxf(m1, __shfl_xor(m1, mm)); ss1 += __shfl_xor(ss1, mm); }
    }
    float invdeg = 1.f / (float)max(degn, 1);
    float sr0 = ssrc[n*HEADS + 0];
    float l0s = leaky(sr0 + sd0 + ss0*invdeg);
    m0 = fmaxf(m0, l0s);
    float l1s = 0.f;
    if (HEADS == 2){
        float sr1 = ssrc[n*HEADS + 1];
        l1s = leaky(sr1 + sd1 + ss1*invdeg);
        m1 = fmaxf(m1, l1s);
    }
    float wself0 = __expf(l0s - m0);
    float wself1 = (HEADS == 2) ? __expf(l1s - m1) : 0.f;

    // scan 2: exp weights + weighted gather of h[src]
    int c = lane % OUTC;      // OUTC=32: both halves duplicate (only lanes<32 write)
    int h = c >> 5;
    float wselfh = (h == 0) ? wself0 : wself1;
    float acc = wselfh * hbuf[(size_t)n*OUTC + c];
    float dl0 = 0.f, dl1 = 0.f;
    for (int p0 = row_start; p0 < row_end; p0 += 64){
        int myp = p0 + lane;
        int srcreg = 0; float w0 = 0.f, w1 = 0.f;
        if (myp < row_end){
            srcreg = csr[myp].x;
            float l0 = leaky(ssrc[srcreg*HEADS + 0] + sd0 + se0[myp]);
            w0 = __expf(l0 - m0);
            if (HEADS == 2){
                float l1 = leaky(ssrc[srcreg*HEADS + 1] + sd1 + se1[myp]);
                w1 = __expf(l1 - m1);
            }
        }
        dl0 += w0; dl1 += w1;
        int cnt = min(64, row_end - p0);
        for (int j = 0; j < cnt; ++j){
            int sj = __shfl(srcreg, j);
            float w0j = __shfl(w0, j);
            float wj = w0j;
            if (HEADS == 2){
                float w1j = __shfl(w1, j);
                wj = (h == 0) ? w0j : w1j;
            }
            acc += wj * hbuf[(size_t)sj*OUTC + c];
        }
    }
    #pragma unroll
    for (int mm = 1; mm < 64; mm <<= 1){
        dl0 += __shfl_xor(dl0, mm);
        if (HEADS == 2) dl1 += __shfl_xor(dl1, mm);
    }
    float den = ((h == 0) ? dl0 : dl1) + wselfh + 1e-16f;
    float o = fmaxf(acc/den + bias[c], 0.f);
    if (lane < OUTC) outbuf[(size_t)n*OUTC + c] = o;
}

// ---------------- pooling + head ----------------
__global__ void pool_kernel(const float* __restrict__ h3, const int* __restrict__ batch,
                            float* __restrict__ pool, float* __restrict__ cnt, int nN){
    __shared__ float accs[GG*32];
    __shared__ float acccnt[GG];
    int tid = threadIdx.x;
    for (int i = tid; i < GG*32; i += 256) accs[i] = 0.f;
    if (tid < GG) acccnt[tid] = 0.f;
    __syncthreads();
    int r = tid >> 5, c = tid & 31;
    int base = blockIdx.x * 512;
    int end = min(base + 512, nN);
    for (int n = base + r; n < end; n += 8){
        int g = batch[n];
        atomicAdd(&accs[g*32 + c], h3[(size_t)n*32 + c]);
        if (c == 0) atomicAdd(&acccnt[g], 1.f);
    }
    __syncthreads();
    for (int i = tid; i < GG*32; i += 256) atomicAdd(&pool[i], accs[i]);
    if (tid < GG) atomicAdd(&cnt[tid], acccnt[tid]);
}

__global__ void final_kernel(const float* __restrict__ pool, const float* __restrict__ cnt,
                             const float* __restrict__ Wf, const float* __restrict__ bf,
                             float* __restrict__ out){
    int g = threadIdx.x;
    if (g >= GG) return;
    float ic = 1.f / fmaxf(cnt[g], 1.f);
    float lg[NCLS];
    #pragma unroll
    for (int k = 0; k < NCLS; ++k) lg[k] = bf[k];
    for (int c = 0; c < 32; ++c){
        float v = pool[g*32 + c] * ic;
        #pragma unroll
        for (int k = 0; k < NCLS; ++k) lg[k] += v * Wf[c*NCLS + k];
    }
    float mx = lg[0];
    #pragma unroll
    for (int k = 1; k < NCLS; ++k) mx = fmaxf(mx, lg[k]);
    float sum = 0.f, ex[NCLS];
    #pragma unroll
    for (int k = 0; k < NCLS; ++k){ ex[k] = expf(lg[k] - mx); sum += ex[k]; }
    #pragma unroll
    for (int k = 0; k < NCLS; ++k) out[g*NCLS + k] = ex[k]/sum;
}

extern "C" void kernel_launch(void* const* d_in, const int* in_sizes, int n_in,
                              void* d_out, int out_size, void* d_ws, size_t ws_size,
                              hipStream_t stream){
    const float* x     = (const float*)d_in[0];
    const int*   eidx  = (const int*)d_in[1];
    const float* eattr = (const float*)d_in[2];
    const int*   batch = (const int*)d_in[3];
    const float* W1 = (const float*)d_in[4];  const float* asrc1 = (const float*)d_in[5];
    const float* adst1 = (const float*)d_in[6]; const float* We1 = (const float*)d_in[7];
    const float* ae1 = (const float*)d_in[8];  const float* b1 = (const float*)d_in[9];
    const float* W2 = (const float*)d_in[10]; const float* asrc2 = (const float*)d_in[11];
    const float* adst2 = (const float*)d_in[12]; const float* We2 = (const float*)d_in[13];
    const float* ae2 = (const float*)d_in[14]; const float* b2 = (const float*)d_in[15];
    const float* W3 = (const float*)d_in[16]; const float* asrc3 = (const float*)d_in[17];
    const float* adst3 = (const float*)d_in[18]; const float* We3 = (const float*)d_in[19];
    const float* ae3 = (const float*)d_in[20]; const float* b3 = (const float*)d_in[21];
    const float* Wf = (const float*)d_in[22]; const float* bf = (const float*)d_in[23];
    float* out = (float*)d_out;

    char* ws = (char*)d_ws;
    int*   deg    = (int*)(ws + OFF_DEG);
    int*   rowptr = (int*)(ws + OFF_ROWPTR);
    int*   cursor = (int*)(ws + OFF_CURSOR);
    int2*  csr    = (int2*)(ws + OFF_CSR);
    float* se     = (float*)(ws + OFF_SE);
    float* ssrc   = (float*)(ws + OFF_SSRC);
    float* sdst   = (float*)(ws + OFF_SDST);
    float* bufH   = (float*)(ws + OFF_BUFH);
    float* bufO   = (float*)(ws + OFF_BUFO);
    float* weff   = (float*)(ws + OFF_WEFF);
    float* pool   = (float*)(ws + OFF_POOL);
    float* cnt    = pool + GG*32;

    const int* srcA = eidx;
    const int* dstA = eidx + EE;

    hipMemsetAsync(deg, 0, (size_t)NN*4, stream);
    hipMemsetAsync(pool, 0, (GG*32 + GG)*4, stream);

    int egrid = (EE + 255)/256;
    deg_kernel<<<egrid, 256, 0, stream>>>(dstA, deg, EE);
    scan_kernel<<<1, 1024, 0, stream>>>(deg, rowptr, cursor, NN);
    fill_kernel<<<egrid, 256, 0, stream>>>(srcA, dstA, cursor, csr, EE);
    weff_kernel<<<1, 128, 0, stream>>>(We1, ae1, We2, ae2, We3, ae3, weff);
    se_kernel<<<egrid, 256, 0, stream>>>(csr, eattr, weff, se, EE);

    int ngrid4 = (NN + 3)/4;
    int ngrid8 = (NN + 7)/8;
    // layer 1
    transform_kernel<64><<<ngrid4, 256, 0, stream>>>(x, W1, asrc1, adst1, bufH, ssrc, sdst, NN);
    agg_kernel<64><<<ngrid4, 256, 0, stream>>>(rowptr, csr, se + 0*(size_t)EE, se + 1*(size_t)EE,
                                               ssrc, sdst, bufH, b1, bufO, NN);
    // layer 2
    transform_kernel<64><<<ngrid4, 256, 0, stream>>>(bufO, W2, asrc2, adst2, bufH, ssrc, sdst, NN);
    agg_kernel<64><<<ngrid4, 256, 0, stream>>>(rowptr, csr, se + 2*(size_t)EE, se + 3*(size_t)EE,
                                               ssrc, sdst, bufH, b2, bufO, NN);
    // layer 3 (1 head, 32 out, no concat -> identity mean)
    transform_kernel<32><<<ngrid8, 256, 0, stream>>>(bufO, W3, asrc3, adst3, bufH, ssrc, sdst, NN);
    agg_kernel<32><<<ngrid4, 256, 0, stream>>>(rowptr, csr, se + 4*(size_t)EE, nullptr,
                                               ssrc, sdst, bufH, b3, bufO, NN);
    // pool + ffn + softmax
    pool_kernel<<<(NN + 511)/512, 256, 0, stream>>>(bufO, batch, pool, cnt, NN);
    final_kernel<<<1, 64, 0, stream>>>(pool, cnt, Wf, bf, out);
}

// Round 2
// 550.780 us; speedup vs baseline: 1.1761x; 1.1761x over previous
//
#include <hip/hip_runtime.h>
#include <math.h>

#define NN 50000
#define EE 1250000
#define GG 16
#define NCLS 5

constexpr size_t AL(size_t x){ return (x + 255) & ~size_t(255); }
constexpr size_t OFF_DEG    = 0;
constexpr size_t OFF_ROWPTR = OFF_DEG + AL((size_t)NN*4);
constexpr size_t OFF_CURSOR = OFF_ROWPTR + AL((size_t)(NN+1)*4);
constexpr size_t OFF_CSR    = OFF_CURSOR + AL((size_t)NN*4);
constexpr size_t OFF_SE     = OFF_CSR + AL((size_t)EE*8);
constexpr size_t OFF_SSRC   = OFF_SE + AL((size_t)EE*5*4);
constexpr size_t OFF_SDST   = OFF_SSRC + AL((size_t)NN*2*4);
constexpr size_t OFF_BUFH   = OFF_SDST + AL((size_t)NN*2*4);
constexpr size_t OFF_BUFO   = OFF_BUFH + AL((size_t)NN*64*4);
constexpr size_t OFF_WEFF   = OFF_BUFO + AL((size_t)NN*64*4);
constexpr size_t OFF_POOL   = OFF_WEFF + AL(80*4);
// pool = GG*32 floats, then cnt = GG floats (contiguous, zeroed together)

__device__ __forceinline__ float leaky(float x){ return x > 0.f ? x : 0.2f*x; }

// ---------------- CSR build ----------------
__global__ void deg_kernel(const int* __restrict__ dst, int* __restrict__ deg, int nE){
    int e = blockIdx.x*256 + threadIdx.x;
    if (e < nE) atomicAdd(&deg[dst[e]], 1);
}

// thread-serial chunks + single 1024-wide scan (~20 barriers total)
__global__ void scan_kernel(const int* __restrict__ deg, int* __restrict__ rowptr,
                            int* __restrict__ cursor, int nN){
    constexpr int CHUNK = 49;  // 1024*49 >= 50000
    __shared__ int s[1024];
    int tid = threadIdx.x;
    int start = tid * CHUNK;
    int end = min(start + CHUNK, nN);
    int sum = 0;
    for (int i = start; i < end; ++i) sum += deg[i];
    s[tid] = sum;
    __syncthreads();
    #pragma unroll
    for (int off = 1; off < 1024; off <<= 1){
        int t = (tid >= off) ? s[tid - off] : 0;
        __syncthreads();
        s[tid] += t;
        __syncthreads();
    }
    int running = s[tid] - sum;  // exclusive prefix of this chunk
    for (int i = start; i < end; ++i){
        rowptr[i] = running;
        cursor[i] = running;
        running += deg[i];
    }
    if (tid == 1023) rowptr[nN] = s[1023];
}

__global__ void fill_kernel(const int* __restrict__ src, const int* __restrict__ dst,
                            int* __restrict__ cursor, int2* __restrict__ csr, int nE){
    int e = blockIdx.x*256 + threadIdx.x;
    if (e < nE){
        int d = dst[e];
        int pos = atomicAdd(&cursor[d], 1);
        csr[pos] = make_int2(src[e], e);
    }
}

// ---------------- edge score precompute ----------------
// weff[j][d] , j: 0=L1h0 1=L1h1 2=L2h0 3=L2h1 4=L3h0
__global__ void weff_kernel(const float* __restrict__ We1, const float* __restrict__ ae1,
                            const float* __restrict__ We2, const float* __restrict__ ae2,
                            const float* __restrict__ We3, const float* __restrict__ ae3,
                            float* __restrict__ weff){
    int t = threadIdx.x;
    if (t >= 80) return;
    int j = t >> 4, d = t & 15;
    const float* We; const float* ae; int hc, h;
    if (j == 0){ We = We1; ae = ae1; hc = 64; h = 0; }
    else if (j == 1){ We = We1; ae = ae1; hc = 64; h = 1; }
    else if (j == 2){ We = We2; ae = ae2; hc = 64; h = 0; }
    else if (j == 3){ We = We2; ae = ae2; hc = 64; h = 1; }
    else { We = We3; ae = ae3; hc = 32; h = 0; }
    float s = 0.f;
    for (int c = 0; c < 32; ++c) s += We[d*hc + h*32 + c] * ae[h*32 + c];
    weff[j*16 + d] = s;
}

// se (SoA, 5 arrays of E) in CSR order: se[j*E + p] = eattr[csr[p].e] . weff[j]
__global__ void se_kernel(const int2* __restrict__ csr, const float* __restrict__ eattr,
                          const float* __restrict__ weff, float* __restrict__ se, int nE){
    __shared__ float w[80];
    int tid = threadIdx.x;
    if (tid < 80) w[tid] = weff[tid];
    __syncthreads();
    int p = blockIdx.x*256 + tid;
    if (p >= nE) return;
    int e = csr[p].y;
    const float4* row = (const float4*)(eattr + (size_t)e*16);
    float4 a0 = row[0], a1 = row[1], a2 = row[2], a3 = row[3];
    float a[16] = {a0.x,a0.y,a0.z,a0.w, a1.x,a1.y,a1.z,a1.w,
                   a2.x,a2.y,a2.z,a2.w, a3.x,a3.y,a3.z,a3.w};
    #pragma unroll
    for (int j = 0; j < 5; ++j){
        float s = 0.f;
        #pragma unroll
        for (int d = 0; d < 16; ++d) s += a[d]*w[j*16+d];
        se[(size_t)j*nE + p] = s;
    }
}

// ---------------- node transform: h = in @ W ; s_src/s_dst fused ----------------
template<int OUTC>
__global__ void transform_kernel(const float* __restrict__ in, const float* __restrict__ W,
                                 const float* __restrict__ asrc, const float* __restrict__ adst,
                                 float* __restrict__ hout, float* __restrict__ ssrc,
                                 float* __restrict__ sdst, int nN){
    constexpr int R = 256/OUTC;
    __shared__ float Ws[64*OUTC];
    __shared__ float ins[R*64];
    int tid = threadIdx.x;
    for (int i = tid; i < 64*OUTC; i += 256) Ws[i] = W[i];
    int base = blockIdx.x * R;
    for (int i = tid; i < R*64; i += 256){
        int n = base + i/64;
        ins[i] = (n < nN) ? in[(size_t)n*64 + (i & 63)] : 0.f;
    }
    __syncthreads();
    int r = tid / OUTC, c = tid % OUTC;
    int n = base + r;
    float acc = 0.f;
    #pragma unroll
    for (int d = 0; d < 64; ++d) acc += ins[r*64 + d] * Ws[d*OUTC + c];
    float ps = acc * asrc[c];
    float pd = acc * adst[c];
    #pragma unroll
    for (int m = 1; m <= 16; m <<= 1){ ps += __shfl_xor(ps, m); pd += __shfl_xor(pd, m); }
    if (n < nN){
        hout[(size_t)n*OUTC + c] = acc;
        constexpr int HEADS = OUTC/32;
        if ((c & 31) == 0){
            int h = c >> 5;
            ssrc[n*HEADS + h] = ps;
            sdst[n*HEADS + h] = pd;
        }
    }
}

// ---------------- per-dst aggregation (one wave per node, SINGLE pass) ----------------
// No max-subtraction: logits are ~N(0,3) (max ~11 << 88), exp() safe in fp32; softmax is
// shift-invariant so result identical. Self-loop s_e = (sum of row's s_e)/deg is
// wave-reduced in the same pass; self term added after the loop (commutative).
template<int OUTC>
__global__ void agg_kernel(const int* __restrict__ rowptr, const int2* __restrict__ csr,
                           const float* __restrict__ se0, const float* __restrict__ se1,
                           const float* __restrict__ ssrc, const float* __restrict__ sdst,
                           const float* __restrict__ hbuf, const float* __restrict__ bias,
                           float* __restrict__ outbuf, int nN){
    constexpr int HEADS = OUTC/32;
    int wid = threadIdx.x >> 6;
    int lane = threadIdx.x & 63;
    int n = blockIdx.x*4 + wid;
    if (n >= nN) return;
    int row_start = rowptr[n], row_end = rowptr[n+1];
    int degn = row_end - row_start;
    float sd0 = sdst[n*HEADS + 0];
    float sd1 = (HEADS == 2) ? sdst[n*HEADS + 1] : 0.f;

    int c = lane % OUTC;      // OUTC=32: both half-waves duplicate (only lanes<32 write)
    int h = c >> 5;

    float acc = 0.f;          // weighted feature accumulator (per lane = per channel)
    float den = 0.f;          // sum of weights (identical across lanes of a head)
    float ssp0 = 0.f, ssp1 = 0.f;  // per-lane partial sums of raw s_e (for self-loop attr)

    for (int p0 = row_start; p0 < row_end; p0 += 64){
        int myp = p0 + lane;
        int srcreg = 0; float w0 = 0.f, w1 = 0.f;
        if (myp < row_end){
            srcreg = csr[myp].x;
            float e0 = se0[myp];
            ssp0 += e0;
            w0 = __expf(leaky(ssrc[srcreg*HEADS + 0] + sd0 + e0));
            if (HEADS == 2){
                float e1 = se1[myp];
                ssp1 += e1;
                w1 = __expf(leaky(ssrc[srcreg*HEADS + 1] + sd1 + e1));
            }
        }
        int cnt = min(64, row_end - p0);
        auto step = [&](int j){
            int sj = __shfl(srcreg, j);
            float wj;
            if (HEADS == 2){
                float wa = __shfl(w0, j), wb = __shfl(w1, j);
                wj = (h == 0) ? wa : wb;
            } else {
                wj = __shfl(w0, j);
            }
            den += wj;
            acc += wj * hbuf[(size_t)sj*OUTC + c];
        };
        int j = 0;
        for (; j + 3 < cnt; j += 4){ step(j); step(j+1); step(j+2); step(j+3); }
        for (; j < cnt; ++j) step(j);
    }

    // reduce raw s_e sums across wave (self-loop mean edge_attr)
    #pragma unroll
    for (int mm = 1; mm < 64; mm <<= 1){
        ssp0 += __shfl_xor(ssp0, mm);
        if (HEADS == 2) ssp1 += __shfl_xor(ssp1, mm);
    }
    float invdeg = 1.f / (float)max(degn, 1);
    float srh = ssrc[n*HEADS + h];
    float sdh = (h == 0) ? sd0 : sd1;
    float ssh = (h == 0) ? ssp0 : ssp1;
    float wself = __expf(leaky(srh + sdh + ssh*invdeg));
    acc += wself * hbuf[(size_t)n*OUTC + c];
    den += wself;

    float o = fmaxf(acc/(den + 1e-16f) + bias[c], 0.f);
    if (lane < OUTC) outbuf[(size_t)n*OUTC + c] = o;
}

// ---------------- pooling + head ----------------
__global__ void pool_kernel(const float* __restrict__ h3, const int* __restrict__ batch,
                            float* __restrict__ pool, float* __restrict__ cnt, int nN){
    __shared__ float accs[GG*32];
    __shared__ float acccnt[GG];
    int tid = threadIdx.x;
    for (int i = tid; i < GG*32; i += 256) accs[i] = 0.f;
    if (tid < GG) acccnt[tid] = 0.f;
    __syncthreads();
    int r = tid >> 5, c = tid & 31;
    int base = blockIdx.x * 512;
    int end = min(base + 512, nN);
    for (int n = base + r; n < end; n += 8){
        int g = batch[n];
        atomicAdd(&accs[g*32 + c], h3[(size_t)n*32 + c]);
        if (c == 0) atomicAdd(&acccnt[g], 1.f);
    }
    __syncthreads();
    for (int i = tid; i < GG*32; i += 256) atomicAdd(&pool[i], accs[i]);
    if (tid < GG) atomicAdd(&cnt[tid], acccnt[tid]);
}

__global__ void final_kernel(const float* __restrict__ pool, const float* __restrict__ cnt,
                             const float* __restrict__ Wf, const float* __restrict__ bf,
                             float* __restrict__ out){
    int g = threadIdx.x;
    if (g >= GG) return;
    float ic = 1.f / fmaxf(cnt[g], 1.f);
    float lg[NCLS];
    #pragma unroll
    for (int k = 0; k < NCLS; ++k) lg[k] = bf[k];
    for (int c = 0; c < 32; ++c){
        float v = pool[g*32 + c] * ic;
        #pragma unroll
        for (int k = 0; k < NCLS; ++k) lg[k] += v * Wf[c*NCLS + k];
    }
    float mx = lg[0];
    #pragma unroll
    for (int k = 1; k < NCLS; ++k) mx = fmaxf(mx, lg[k]);
    float sum = 0.f, ex[NCLS];
    #pragma unroll
    for (int k = 0; k < NCLS; ++k){ ex[k] = expf(lg[k] - mx); sum += ex[k]; }
    #pragma unroll
    for (int k = 0; k < NCLS; ++k) out[g*NCLS + k] = ex[k]/sum;
}

extern "C" void kernel_launch(void* const* d_in, const int* in_sizes, int n_in,
                              void* d_out, int out_size, void* d_ws, size_t ws_size,
                              hipStream_t stream){
    const float* x     = (const float*)d_in[0];
    const int*   eidx  = (const int*)d_in[1];
    const float* eattr = (const float*)d_in[2];
    const int*   batch = (const int*)d_in[3];
    const float* W1 = (const float*)d_in[4];  const float* asrc1 = (const float*)d_in[5];
    const float* adst1 = (const float*)d_in[6]; const float* We1 = (const float*)d_in[7];
    const float* ae1 = (const float*)d_in[8];  const float* b1 = (const float*)d_in[9];
    const float* W2 = (const float*)d_in[10]; const float* asrc2 = (const float*)d_in[11];
    const float* adst2 = (const float*)d_in[12]; const float* We2 = (const float*)d_in[13];
    const float* ae2 = (const float*)d_in[14]; const float* b2 = (const float*)d_in[15];
    const float* W3 = (const float*)d_in[16]; const float* asrc3 = (const float*)d_in[17];
    const float* adst3 = (const float*)d_in[18]; const float* We3 = (const float*)d_in[19];
    const float* ae3 = (const float*)d_in[20]; const float* b3 = (const float*)d_in[21];
    const float* Wf = (const float*)d_in[22]; const float* bf = (const float*)d_in[23];
    float* out = (float*)d_out;

    char* ws = (char*)d_ws;
    int*   deg    = (int*)(ws + OFF_DEG);
    int*   rowptr = (int*)(ws + OFF_ROWPTR);
    int*   cursor = (int*)(ws + OFF_CURSOR);
    int2*  csr    = (int2*)(ws + OFF_CSR);
    float* se     = (float*)(ws + OFF_SE);
    float* ssrc   = (float*)(ws + OFF_SSRC);
    float* sdst   = (float*)(ws + OFF_SDST);
    float* bufH   = (float*)(ws + OFF_BUFH);
    float* bufO   = (float*)(ws + OFF_BUFO);
    float* weff   = (float*)(ws + OFF_WEFF);
    float* pool   = (float*)(ws + OFF_POOL);
    float* cnt    = pool + GG*32;

    const int* srcA = eidx;
    const int* dstA = eidx + EE;

    hipMemsetAsync(deg, 0, (size_t)NN*4, stream);
    hipMemsetAsync(pool, 0, (GG*32 + GG)*4, stream);

    int egrid = (EE + 255)/256;
    deg_kernel<<<egrid, 256, 0, stream>>>(dstA, deg, EE);
    scan_kernel<<<1, 1024, 0, stream>>>(deg, rowptr, cursor, NN);
    fill_kernel<<<egrid, 256, 0, stream>>>(srcA, dstA, cursor, csr, EE);
    weff_kernel<<<1, 128, 0, stream>>>(We1, ae1, We2, ae2, We3, ae3, weff);
    se_kernel<<<egrid, 256, 0, stream>>>(csr, eattr, weff, se, EE);

    int ngrid4 = (NN + 3)/4;
    int ngrid8 = (NN + 7)/8;
    // layer 1
    transform_kernel<64><<<ngrid4, 256, 0, stream>>>(x, W1, asrc1, adst1, bufH, ssrc, sdst, NN);
    agg_kernel<64><<<ngrid4, 256, 0, stream>>>(rowptr, csr, se + 0*(size_t)EE, se + 1*(size_t)EE,
                                               ssrc, sdst, bufH, b1, bufO, NN);
    // layer 2
    transform_kernel<64><<<ngrid4, 256, 0, stream>>>(bufO, W2, asrc2, adst2, bufH, ssrc, sdst, NN);
    agg_kernel<64><<<ngrid4, 256, 0, stream>>>(rowptr, csr, se + 2*(size_t)EE, se + 3*(size_t)EE,
                                               ssrc, sdst, bufH, b2, bufO, NN);
    // layer 3 (1 head, 32 out, no concat -> identity mean)
    transform_kernel<32><<<ngrid8, 256, 0, stream>>>(bufO, W3, asrc3, adst3, bufH, ssrc, sdst, NN);
    agg_kernel<32><<<ngrid4, 256, 0, stream>>>(rowptr, csr, se + 4*(size_t)EE, nullptr,
                                               ssrc, sdst, bufH, b3, bufO, NN);
    // pool + ffn + softmax
    pool_kernel<<<(NN + 511)/512, 256, 0, stream>>>(bufO, batch, pool, cnt, NN);
    final_kernel<<<1, 64, 0, stream>>>(pool, cnt, Wf, bf, out);
}

// Round 3
// 384.626 us; speedup vs baseline: 1.6842x; 1.4320x over previous
//
#include <hip/hip_runtime.h>
#include <math.h>

#define NN 50000
#define EE 1250000
#define GG 16
#define NCLS 5
#define NBIN 391        // ceil(50000 / 128)
#define BINSHIFT 7
#define CAPB 3900       // max edges per bin (mean 3198, sd ~57 -> 12 sigma headroom)

constexpr size_t AL(size_t x){ return (x + 255) & ~size_t(255); }
constexpr size_t OFF_DEG    = 0;
constexpr size_t OFF_ROWPTR = OFF_DEG + AL((size_t)NN*4);
constexpr size_t OFF_CURSOR = OFF_ROWPTR + AL((size_t)(NN+1)*4);   // bincursor/bsum/boff live here
constexpr size_t OFF_CSR    = OFF_CURSOR + AL((size_t)NN*4);
constexpr size_t OFF_SE     = OFF_CSR + AL((size_t)EE*8);
constexpr size_t OFF_SSRC   = OFF_SE + AL((size_t)EE*5*4);
constexpr size_t OFF_SDST   = OFF_SSRC + AL((size_t)NN*2*4);
constexpr size_t OFF_BUFH   = OFF_SDST + AL((size_t)NN*2*4);       // also staging for bin sort
constexpr size_t OFF_BUFO   = OFF_BUFH + AL((size_t)NN*64*4);
constexpr size_t OFF_WEFF   = OFF_BUFO + AL((size_t)NN*64*4);
constexpr size_t OFF_POOL   = OFF_WEFF + AL(80*4);
// pool = GG*32 floats, then cnt = GG floats (contiguous, zeroed together)

__device__ __forceinline__ float leaky(float x){ return x > 0.f ? x : 0.2f*x; }

// ---------------- CSR build ----------------
__global__ void deg_kernel(const int* __restrict__ dst, int* __restrict__ deg, int nE){
    int e = blockIdx.x*256 + threadIdx.x;
    if (e < nE) atomicAdd(&deg[dst[e]], 1);
}

// parallel scan: block sums -> scan of 49 sums -> per-block local scan
__global__ void bsum_kernel(const int* __restrict__ deg, int* __restrict__ bsum, int nN){
    __shared__ int s[1024];
    int tid = threadIdx.x;
    int i = blockIdx.x*1024 + tid;
    s[tid] = (i < nN) ? deg[i] : 0;
    __syncthreads();
    for (int off = 512; off > 0; off >>= 1){
        if (tid < off) s[tid] += s[tid+off];
        __syncthreads();
    }
    if (tid == 0) bsum[blockIdx.x] = s[0];
}

__global__ void bscan_kernel(const int* __restrict__ bsum, int* __restrict__ boff,
                             int* __restrict__ rowptr, int nB, int nN){
    int lane = threadIdx.x;  // 64
    int v = (lane < nB) ? bsum[lane] : 0;
    int incl = v;
    #pragma unroll
    for (int off = 1; off < 64; off <<= 1){
        int t = __shfl_up(incl, off);
        if (lane >= off) incl += t;
    }
    if (lane < nB) boff[lane] = incl - v;
    if (lane == 63) rowptr[nN] = incl;  // lanes >= nB contributed 0
}

__global__ void wptr_kernel(const int* __restrict__ deg, const int* __restrict__ boff,
                            int* __restrict__ rowptr, int nN){
    __shared__ int s[1024];
    int tid = threadIdx.x;
    int i = blockIdx.x*1024 + tid;
    int v = (i < nN) ? deg[i] : 0;
    s[tid] = v;
    __syncthreads();
    for (int off = 1; off < 1024; off <<= 1){
        int t = (tid >= off) ? s[tid-off] : 0;
        __syncthreads();
        s[tid] += t;
        __syncthreads();
    }
    if (i < nN) rowptr[i] = boff[blockIdx.x] + s[tid] - v;
}

__global__ void binit_kernel(const int* __restrict__ rowptr, int* __restrict__ bincursor){
    int b = blockIdx.x*256 + threadIdx.x;
    if (b < NBIN) bincursor[b] = rowptr[b << BINSHIFT];
}

// pass A: bin edges by dst>>7 into staging regions (== csr layout), time-local dense writes
__global__ void binA_kernel(const int* __restrict__ src, const int* __restrict__ dst,
                            int* __restrict__ bincursor, int2* __restrict__ staging, int nE){
    __shared__ int lcount[NBIN];
    __shared__ int lbase[NBIN];
    int tid = threadIdx.x;  // 1024
    for (int i = tid; i < NBIN; i += 1024) lcount[i] = 0;
    __syncthreads();
    int base = blockIdx.x * 8192;
    int w0[8], eid[8], bn[8], idx[8];
    #pragma unroll
    for (int k = 0; k < 8; ++k){
        int i = base + k*1024 + tid;
        if (i < nE){
            int d = dst[i];
            int s = src[i];                   // < 65536, fits 16 bits
            bn[k]  = d >> BINSHIFT;
            w0[k]  = s | ((d & 127) << 16);
            eid[k] = i;
            idx[k] = atomicAdd(&lcount[bn[k]], 1);
        } else bn[k] = -1;
    }
    __syncthreads();
    for (int i = tid; i < NBIN; i += 1024)
        lbase[i] = atomicAdd(&bincursor[i], lcount[i]);
    __syncthreads();
    #pragma unroll
    for (int k = 0; k < 8; ++k)
        if (bn[k] >= 0)
            staging[lbase[bn[k]] + idx[k]] = make_int2(w0[k], eid[k]);
}

// pass B: per-bin LDS reorder -> fully sorted CSR, coalesced writes
__global__ void binB_kernel(const int* __restrict__ rowptr, const int2* __restrict__ staging,
                            int2* __restrict__ csr, int nN){
    __shared__ int2 lin[CAPB];
    __shared__ int2 lout[CAPB];
    __shared__ int lcnt[128];
    int b = blockIdx.x;
    int lo = b << BINSHIFT;
    int hi = min(lo + 128, nN);
    int r0 = rowptr[lo], r1 = rowptr[hi];
    int cnt = r1 - r0;
    int tid = threadIdx.x;  // 1024
    if (tid < 128) lcnt[tid] = 0;
    for (int k = tid; k < cnt && k < CAPB; k += 1024) lin[k] = staging[r0 + k];
    __syncthreads();
    for (int k = tid; k < cnt; k += 1024){
        int2 v = (k < CAPB) ? lin[k] : staging[r0 + k];
        int dl = v.x >> 16;
        int rank = atomicAdd(&lcnt[dl], 1);
        int target = rowptr[lo + dl] - r0 + rank;
        int2 outv = make_int2(v.x & 0xFFFF, v.y);
        if (target < CAPB) lout[target] = outv;
        else csr[r0 + target] = outv;
    }
    __syncthreads();
    int m = min(cnt, CAPB);
    for (int k = tid; k < m; k += 1024) csr[r0 + k] = lout[k];
}

// ---------------- edge score precompute ----------------
// weff[j][d] , j: 0=L1h0 1=L1h1 2=L2h0 3=L2h1 4=L3h0
__global__ void weff_kernel(const float* __restrict__ We1, const float* __restrict__ ae1,
                            const float* __restrict__ We2, const float* __restrict__ ae2,
                            const float* __restrict__ We3, const float* __restrict__ ae3,
                            float* __restrict__ weff){
    int t = threadIdx.x;
    if (t >= 80) return;
    int j = t >> 4, d = t & 15;
    const float* We; const float* ae; int hc, h;
    if (j == 0){ We = We1; ae = ae1; hc = 64; h = 0; }
    else if (j == 1){ We = We1; ae = ae1; hc = 64; h = 1; }
    else if (j == 2){ We = We2; ae = ae2; hc = 64; h = 0; }
    else if (j == 3){ We = We2; ae = ae2; hc = 64; h = 1; }
    else { We = We3; ae = ae3; hc = 32; h = 0; }
    float s = 0.f;
    for (int c = 0; c < 32; ++c) s += We[d*hc + h*32 + c] * ae[h*32 + c];
    weff[j*16 + d] = s;
}

// se (SoA, 5 arrays of E) in CSR order: se[j*E + p] = eattr[csr[p].e] . weff[j]
__global__ void se_kernel(const int2* __restrict__ csr, const float* __restrict__ eattr,
                          const float* __restrict__ weff, float* __restrict__ se, int nE){
    __shared__ float w[80];
    int tid = threadIdx.x;
    if (tid < 80) w[tid] = weff[tid];
    __syncthreads();
    int p = blockIdx.x*256 + tid;
    if (p >= nE) return;
    int e = csr[p].y;
    const float4* row = (const float4*)(eattr + (size_t)e*16);
    float4 a0 = row[0], a1 = row[1], a2 = row[2], a3 = row[3];
    float a[16] = {a0.x,a0.y,a0.z,a0.w, a1.x,a1.y,a1.z,a1.w,
                   a2.x,a2.y,a2.z,a2.w, a3.x,a3.y,a3.z,a3.w};
    #pragma unroll
    for (int j = 0; j < 5; ++j){
        float s = 0.f;
        #pragma unroll
        for (int d = 0; d < 16; ++d) s += a[d]*w[j*16+d];
        se[(size_t)j*nE + p] = s;
    }
}

// ---------------- node transform: h = in @ W ; s_src/s_dst fused ----------------
template<int OUTC>
__global__ void transform_kernel(const float* __restrict__ in, const float* __restrict__ W,
                                 const float* __restrict__ asrc, const float* __restrict__ adst,
                                 float* __restrict__ hout, float* __restrict__ ssrc,
                                 float* __restrict__ sdst, int nN){
    constexpr int R = 256/OUTC;
    __shared__ float Ws[64*OUTC];
    __shared__ float ins[R*64];
    int tid = threadIdx.x;
    for (int i = tid; i < 64*OUTC; i += 256) Ws[i] = W[i];
    int base = blockIdx.x * R;
    for (int i = tid; i < R*64; i += 256){
        int n = base + i/64;
        ins[i] = (n < nN) ? in[(size_t)n*64 + (i & 63)] : 0.f;
    }
    __syncthreads();
    int r = tid / OUTC, c = tid % OUTC;
    int n = base + r;
    float acc = 0.f;
    #pragma unroll
    for (int d = 0; d < 64; ++d) acc += ins[r*64 + d] * Ws[d*OUTC + c];
    float ps = acc * asrc[c];
    float pd = acc * adst[c];
    #pragma unroll
    for (int m = 1; m <= 16; m <<= 1){ ps += __shfl_xor(ps, m); pd += __shfl_xor(pd, m); }
    if (n < nN){
        hout[(size_t)n*OUTC + c] = acc;
        constexpr int HEADS = OUTC/32;
        if ((c & 31) == 0){
            int h = c >> 5;
            ssrc[n*HEADS + h] = ps;
            sdst[n*HEADS + h] = pd;
        }
    }
}

// ---------------- per-dst aggregation (one wave per node, SINGLE pass) ----------------
// No max-subtraction: logits ~N(0,3) (max ~11 << 88), exp safe in fp32; softmax shift-invariant.
template<int OUTC>
__global__ void agg_kernel(const int* __restrict__ rowptr, const int2* __restrict__ csr,
                           const float* __restrict__ se0, const float* __restrict__ se1,
                           const float* __restrict__ ssrc, const float* __restrict__ sdst,
                           const float* __restrict__ hbuf, const float* __restrict__ bias,
                           float* __restrict__ outbuf, int nN){
    constexpr int HEADS = OUTC/32;
    int wid = threadIdx.x >> 6;
    int lane = threadIdx.x & 63;
    int n = blockIdx.x*4 + wid;
    if (n >= nN) return;
    int row_start = rowptr[n], row_end = rowptr[n+1];
    int degn = row_end - row_start;
    float sd0 = sdst[n*HEADS + 0];
    float sd1 = (HEADS == 2) ? sdst[n*HEADS + 1] : 0.f;

    int c = lane % OUTC;
    int h = c >> 5;

    float acc = 0.f;
    float den = 0.f;
    float ssp0 = 0.f, ssp1 = 0.f;

    for (int p0 = row_start; p0 < row_end; p0 += 64){
        int myp = p0 + lane;
        int srcreg = 0; float w0 = 0.f, w1 = 0.f;
        if (myp < row_end){
            srcreg = csr[myp].x;
            float e0 = se0[myp];
            ssp0 += e0;
            w0 = __expf(leaky(ssrc[srcreg*HEADS + 0] + sd0 + e0));
            if (HEADS == 2){
                float e1 = se1[myp];
                ssp1 += e1;
                w1 = __expf(leaky(ssrc[srcreg*HEADS + 1] + sd1 + e1));
            }
        }
        int cnt = min(64, row_end - p0);
        auto step = [&](int j){
            int sj = __shfl(srcreg, j);
            float wj;
            if (HEADS == 2){
                float wa = __shfl(w0, j), wb = __shfl(w1, j);
                wj = (h == 0) ? wa : wb;
            } else {
                wj = __shfl(w0, j);
            }
            den += wj;
            acc += wj * hbuf[(size_t)sj*OUTC + c];
        };
        int j = 0;
        for (; j + 3 < cnt; j += 4){ step(j); step(j+1); step(j+2); step(j+3); }
        for (; j < cnt; ++j) step(j);
    }

    #pragma unroll
    for (int mm = 1; mm < 64; mm <<= 1){
        ssp0 += __shfl_xor(ssp0, mm);
        if (HEADS == 2) ssp1 += __shfl_xor(ssp1, mm);
    }
    float invdeg = 1.f / (float)max(degn, 1);
    float srh = ssrc[n*HEADS + h];
    float sdh = (h == 0) ? sd0 : sd1;
    float ssh = (h == 0) ? ssp0 : ssp1;
    float wself = __expf(leaky(srh + sdh + ssh*invdeg));
    acc += wself * hbuf[(size_t)n*OUTC + c];
    den += wself;

    float o = fmaxf(acc/(den + 1e-16f) + bias[c], 0.f);
    if (lane < OUTC) outbuf[(size_t)n*OUTC + c] = o;
}

// ---------------- pooling + head ----------------
__global__ void pool_kernel(const float* __restrict__ h3, const int* __restrict__ batch,
                            float* __restrict__ pool, float* __restrict__ cnt, int nN){
    __shared__ float accs[GG*32];
    __shared__ float acccnt[GG];
    int tid = threadIdx.x;
    for (int i = tid; i < GG*32; i += 256) accs[i] = 0.f;
    if (tid < GG) acccnt[tid] = 0.f;
    __syncthreads();
    int r = tid >> 5, c = tid & 31;
    int base = blockIdx.x * 512;
    int end = min(base + 512, nN);
    for (int n = base + r; n < end; n += 8){
        int g = batch[n];
        atomicAdd(&accs[g*32 + c], h3[(size_t)n*32 + c]);
        if (c == 0) atomicAdd(&acccnt[g], 1.f);
    }
    __syncthreads();
    for (int i = tid; i < GG*32; i += 256) atomicAdd(&pool[i], accs[i]);
    if (tid < GG) atomicAdd(&cnt[tid], acccnt[tid]);
}

__global__ void final_kernel(const float* __restrict__ pool, const float* __restrict__ cnt,
                             const float* __restrict__ Wf, const float* __restrict__ bf,
                             float* __restrict__ out){
    int g = threadIdx.x;
    if (g >= GG) return;
    float ic = 1.f / fmaxf(cnt[g], 1.f);
    float lg[NCLS];
    #pragma unroll
    for (int k = 0; k < NCLS; ++k) lg[k] = bf[k];
    for (int c = 0; c < 32; ++c){
        float v = pool[g*32 + c] * ic;
        #pragma unroll
        for (int k = 0; k < NCLS; ++k) lg[k] += v * Wf[c*NCLS + k];
    }
    float mx = lg[0];
    #pragma unroll
    for (int k = 1; k < NCLS; ++k) mx = fmaxf(mx, lg[k]);
    float sum = 0.f, ex[NCLS];
    #pragma unroll
    for (int k = 0; k < NCLS; ++k){ ex[k] = expf(lg[k] - mx); sum += ex[k]; }
    #pragma unroll
    for (int k = 0; k < NCLS; ++k) out[g*NCLS + k] = ex[k]/sum;
}

extern "C" void kernel_launch(void* const* d_in, const int* in_sizes, int n_in,
                              void* d_out, int out_size, void* d_ws, size_t ws_size,
                              hipStream_t stream){
    const float* x     = (const float*)d_in[0];
    const int*   eidx  = (const int*)d_in[1];
    const float* eattr = (const float*)d_in[2];
    const int*   batch = (const int*)d_in[3];
    const float* W1 = (const float*)d_in[4];  const float* asrc1 = (const float*)d_in[5];
    const float* adst1 = (const float*)d_in[6]; const float* We1 = (const float*)d_in[7];
    const float* ae1 = (const float*)d_in[8];  const float* b1 = (const float*)d_in[9];
    const float* W2 = (const float*)d_in[10]; const float* asrc2 = (const float*)d_in[11];
    const float* adst2 = (const float*)d_in[12]; const float* We2 = (const float*)d_in[13];
    const float* ae2 = (const float*)d_in[14]; const float* b2 = (const float*)d_in[15];
    const float* W3 = (const float*)d_in[16]; const float* asrc3 = (const float*)d_in[17];
    const float* adst3 = (const float*)d_in[18]; const float* We3 = (const float*)d_in[19];
    const float* ae3 = (const float*)d_in[20]; const float* b3 = (const float*)d_in[21];
    const float* Wf = (const float*)d_in[22]; const float* bf = (const float*)d_in[23];
    float* out = (float*)d_out;

    char* ws = (char*)d_ws;
    int*   deg    = (int*)(ws + OFF_DEG);
    int*   rowptr = (int*)(ws + OFF_ROWPTR);
    int*   curs   = (int*)(ws + OFF_CURSOR);   // bincursor @0, bsum @512, boff @1024
    int2*  csr    = (int2*)(ws + OFF_CSR);
    float* se     = (float*)(ws + OFF_SE);
    float* ssrc   = (float*)(ws + OFF_SSRC);
    float* sdst   = (float*)(ws + OFF_SDST);
    float* bufH   = (float*)(ws + OFF_BUFH);
    float* bufO   = (float*)(ws + OFF_BUFO);
    float* weff   = (float*)(ws + OFF_WEFF);
    float* pool   = (float*)(ws + OFF_POOL);
    float* cnt    = pool + GG*32;

    int* bincursor = curs;
    int* bsum      = curs + 512;
    int* boff      = curs + 1024;
    int2* staging  = (int2*)bufH;   // bufH dead until transforms; 10MB <= 12.8MB

    const int* srcA = eidx;
    const int* dstA = eidx + EE;

    hipMemsetAsync(deg, 0, (size_t)NN*4, stream);
    hipMemsetAsync(pool, 0, (GG*32 + GG)*4, stream);

    int egrid = (EE + 255)/256;
    deg_kernel<<<egrid, 256, 0, stream>>>(dstA, deg, EE);
    int sgrid = (NN + 1023)/1024;  // 49
    bsum_kernel<<<sgrid, 1024, 0, stream>>>(deg, bsum, NN);
    bscan_kernel<<<1, 64, 0, stream>>>(bsum, boff, rowptr, sgrid, NN);
    wptr_kernel<<<sgrid, 1024, 0, stream>>>(deg, boff, rowptr, NN);
    binit_kernel<<<(NBIN+255)/256, 256, 0, stream>>>(rowptr, bincursor);
    binA_kernel<<<(EE + 8191)/8192, 1024, 0, stream>>>(srcA, dstA, bincursor, staging, EE);
    binB_kernel<<<NBIN, 1024, 0, stream>>>(rowptr, staging, csr, NN);

    weff_kernel<<<1, 128, 0, stream>>>(We1, ae1, We2, ae2, We3, ae3, weff);
    se_kernel<<<egrid, 256, 0, stream>>>(csr, eattr, weff, se, EE);

    int ngrid4 = (NN + 3)/4;
    int ngrid8 = (NN + 7)/8;
    // layer 1
    transform_kernel<64><<<ngrid4, 256, 0, stream>>>(x, W1, asrc1, adst1, bufH, ssrc, sdst, NN);
    agg_kernel<64><<<ngrid4, 256, 0, stream>>>(rowptr, csr, se + 0*(size_t)EE, se + 1*(size_t)EE,
                                               ssrc, sdst, bufH, b1, bufO, NN);
    // layer 2
    transform_kernel<64><<<ngrid4, 256, 0, stream>>>(bufO, W2, asrc2, adst2, bufH, ssrc, sdst, NN);
    agg_kernel<64><<<ngrid4, 256, 0, stream>>>(rowptr, csr, se + 2*(size_t)EE, se + 3*(size_t)EE,
                                               ssrc, sdst, bufH, b2, bufO, NN);
    // layer 3 (1 head, 32 out, no concat -> identity mean)
    transform_kernel<32><<<ngrid8, 256, 0, stream>>>(bufO, W3, asrc3, adst3, bufH, ssrc, sdst, NN);
    agg_kernel<32><<<ngrid4, 256, 0, stream>>>(rowptr, csr, se + 4*(size_t)EE, nullptr,
                                               ssrc, sdst, bufH, b3, bufO, NN);
    // pool + ffn + softmax
    pool_kernel<<<(NN + 511)/512, 256, 0, stream>>>(bufO, batch, pool, cnt, NN);
    final_kernel<<<1, 64, 0, stream>>>(pool, cnt, Wf, bf, out);
}

// Round 4
// 375.948 us; speedup vs baseline: 1.7231x; 1.0231x over previous
//
#include <hip/hip_runtime.h>
#include <math.h>

#define NN 50000
#define EE 1250000
#define GG 16
#define NCLS 5
#define NBIN 391        // ceil(50000 / 128)
#define BINSHIFT 7
#define CAPB 3900       // max edges per bin (mean 3200, sigma ~57 -> 12 sigma headroom)

constexpr size_t AL(size_t x){ return (x + 255) & ~size_t(255); }
constexpr size_t OFF_DEG    = 0;
constexpr size_t OFF_ROWPTR = OFF_DEG + AL((size_t)NN*4);
constexpr size_t OFF_CURSOR = OFF_ROWPTR + AL((size_t)(NN+1)*4);   // bincursor/bsum/boff
constexpr size_t OFF_CSR    = OFF_CURSOR + AL((size_t)NN*4);       // srcs(ushort E) + eid(int E)
constexpr size_t OFF_EID    = OFF_CSR + AL((size_t)EE*2);
constexpr size_t OFF_SE     = OFF_CSR + AL((size_t)EE*8);
constexpr size_t OFF_SSRC   = OFF_SE + AL((size_t)EE*5*4);
constexpr size_t OFF_SDST   = OFF_SSRC + AL((size_t)NN*2*4);
constexpr size_t OFF_BUFH   = OFF_SDST + AL((size_t)NN*2*4);       // bf16x2 h; also bin staging
constexpr size_t OFF_BUFO   = OFF_BUFH + AL((size_t)NN*64*4);
constexpr size_t OFF_WEFF   = OFF_BUFO + AL((size_t)NN*64*4);
constexpr size_t OFF_POOL   = OFF_WEFF + AL(80*4);

__device__ __forceinline__ float leaky(float x){ return x > 0.f ? x : 0.2f*x; }
__device__ __forceinline__ unsigned rne_bf16(float x){
    unsigned u = __float_as_uint(x);
    return (u + 0x7FFFu + ((u >> 16) & 1u)) >> 16;
}

// ---------------- CSR build ----------------
__global__ void deg_kernel(const int* __restrict__ dst, int* __restrict__ deg, int nE){
    int e = blockIdx.x*256 + threadIdx.x;
    if (e < nE) atomicAdd(&deg[dst[e]], 1);
}

__global__ void bsum_kernel(const int* __restrict__ deg, int* __restrict__ bsum, int nN){
    __shared__ int s[1024];
    int tid = threadIdx.x;
    int i = blockIdx.x*1024 + tid;
    s[tid] = (i < nN) ? deg[i] : 0;
    __syncthreads();
    for (int off = 512; off > 0; off >>= 1){
        if (tid < off) s[tid] += s[tid+off];
        __syncthreads();
    }
    if (tid == 0) bsum[blockIdx.x] = s[0];
}

__global__ void bscan_kernel(const int* __restrict__ bsum, int* __restrict__ boff,
                             int* __restrict__ rowptr, int nB, int nN){
    int lane = threadIdx.x;  // 64
    int v = (lane < nB) ? bsum[lane] : 0;
    int incl = v;
    #pragma unroll
    for (int off = 1; off < 64; off <<= 1){
        int t = __shfl_up(incl, off);
        if (lane >= off) incl += t;
    }
    if (lane < nB) boff[lane] = incl - v;
    if (lane == 63) rowptr[nN] = incl;
}

__global__ void wptr_kernel(const int* __restrict__ deg, const int* __restrict__ boff,
                            int* __restrict__ rowptr, int nN){
    __shared__ int s[1024];
    int tid = threadIdx.x;
    int i = blockIdx.x*1024 + tid;
    int v = (i < nN) ? deg[i] : 0;
    s[tid] = v;
    __syncthreads();
    for (int off = 1; off < 1024; off <<= 1){
        int t = (tid >= off) ? s[tid-off] : 0;
        __syncthreads();
        s[tid] += t;
        __syncthreads();
    }
    if (i < nN) rowptr[i] = boff[blockIdx.x] + s[tid] - v;
}

__global__ void binit_kernel(const int* __restrict__ rowptr, int* __restrict__ bincursor){
    int b = blockIdx.x*256 + threadIdx.x;
    if (b < NBIN) bincursor[b] = rowptr[b << BINSHIFT];
}

__global__ void binA_kernel(const int* __restrict__ src, const int* __restrict__ dst,
                            int* __restrict__ bincursor, int2* __restrict__ staging, int nE){
    __shared__ int lcount[NBIN];
    __shared__ int lbase[NBIN];
    int tid = threadIdx.x;  // 1024
    for (int i = tid; i < NBIN; i += 1024) lcount[i] = 0;
    __syncthreads();
    int base = blockIdx.x * 8192;
    int w0[8], eid[8], bn[8], idx[8];
    #pragma unroll
    for (int k = 0; k < 8; ++k){
        int i = base + k*1024 + tid;
        if (i < nE){
            int d = dst[i];
            int s = src[i];                   // < 65536, fits 16 bits
            bn[k]  = d >> BINSHIFT;
            w0[k]  = s | ((d & 127) << 16);
            eid[k] = i;
            idx[k] = atomicAdd(&lcount[bn[k]], 1);
        } else bn[k] = -1;
    }
    __syncthreads();
    for (int i = tid; i < NBIN; i += 1024)
        lbase[i] = atomicAdd(&bincursor[i], lcount[i]);
    __syncthreads();
    #pragma unroll
    for (int k = 0; k < 8; ++k)
        if (bn[k] >= 0)
            staging[lbase[bn[k]] + idx[k]] = make_int2(w0[k], eid[k]);
}

// pass B: per-bin LDS reorder -> srcs (ushort) + eid (int), coalesced writes
__global__ void binB_kernel(const int* __restrict__ rowptr, const int2* __restrict__ staging,
                            unsigned short* __restrict__ srcs, int* __restrict__ eidA, int nN){
    __shared__ int2 lin[CAPB];
    __shared__ int2 lout[CAPB];
    __shared__ int lcnt[128];
    int b = blockIdx.x;
    int lo = b << BINSHIFT;
    int hi = min(lo + 128, nN);
    int r0 = rowptr[lo], r1 = rowptr[hi];
    int cnt = r1 - r0;
    int tid = threadIdx.x;  // 1024
    if (tid < 128) lcnt[tid] = 0;
    for (int k = tid; k < cnt && k < CAPB; k += 1024) lin[k] = staging[r0 + k];
    __syncthreads();
    for (int k = tid; k < cnt; k += 1024){
        int2 v = (k < CAPB) ? lin[k] : staging[r0 + k];
        int dl = v.x >> 16;
        int rank = atomicAdd(&lcnt[dl], 1);
        int target = rowptr[lo + dl] - r0 + rank;
        int2 outv = make_int2(v.x & 0xFFFF, v.y);
        if (target < CAPB) lout[target] = outv;
        else { srcs[r0 + target] = (unsigned short)outv.x; eidA[r0 + target] = outv.y; }
    }
    __syncthreads();
    int m = min(cnt, CAPB);
    for (int k = tid; k < m; k += 1024){
        srcs[r0 + k] = (unsigned short)lout[k].x;
        eidA[r0 + k] = lout[k].y;
    }
}

// ---------------- edge score precompute ----------------
__global__ void weff_kernel(const float* __restrict__ We1, const float* __restrict__ ae1,
                            const float* __restrict__ We2, const float* __restrict__ ae2,
                            const float* __restrict__ We3, const float* __restrict__ ae3,
                            float* __restrict__ weff){
    int t = threadIdx.x;
    if (t >= 80) return;
    int j = t >> 4, d = t & 15;
    const float* We; const float* ae; int hc, h;
    if (j == 0){ We = We1; ae = ae1; hc = 64; h = 0; }
    else if (j == 1){ We = We1; ae = ae1; hc = 64; h = 1; }
    else if (j == 2){ We = We2; ae = ae2; hc = 64; h = 0; }
    else if (j == 3){ We = We2; ae = ae2; hc = 64; h = 1; }
    else { We = We3; ae = ae3; hc = 32; h = 0; }
    float s = 0.f;
    for (int c = 0; c < 32; ++c) s += We[d*hc + h*32 + c] * ae[h*32 + c];
    weff[j*16 + d] = s;
}

__global__ void se_kernel(const int* __restrict__ eidA, const float* __restrict__ eattr,
                          const float* __restrict__ weff, float* __restrict__ se, int nE){
    __shared__ float w[80];
    int tid = threadIdx.x;
    if (tid < 80) w[tid] = weff[tid];
    __syncthreads();
    int p = blockIdx.x*256 + tid;
    if (p >= nE) return;
    int e = eidA[p];
    const float4* row = (const float4*)(eattr + (size_t)e*16);
    float4 a0 = row[0], a1 = row[1], a2 = row[2], a3 = row[3];
    float a[16] = {a0.x,a0.y,a0.z,a0.w, a1.x,a1.y,a1.z,a1.w,
                   a2.x,a2.y,a2.z,a2.w, a3.x,a3.y,a3.z,a3.w};
    #pragma unroll
    for (int j = 0; j < 5; ++j){
        float s = 0.f;
        #pragma unroll
        for (int d = 0; d < 16; ++d) s += a[d]*w[j*16+d];
        se[(size_t)j*nE + p] = s;
    }
}

// ---------------- node transform: h = in @ W (bf16x2 packed out); s_src/s_dst fused ----
template<int OUTC>
__global__ void transform_kernel(const float* __restrict__ in, const float* __restrict__ W,
                                 const float* __restrict__ asrc, const float* __restrict__ adst,
                                 unsigned* __restrict__ hout2, float* __restrict__ ssrc,
                                 float* __restrict__ sdst, int nN){
    constexpr int R = 256/OUTC;
    __shared__ float Ws[64*OUTC];
    __shared__ float ins[R*64];
    int tid = threadIdx.x;
    for (int i = tid; i < 64*OUTC; i += 256) Ws[i] = W[i];
    int base = blockIdx.x * R;
    for (int i = tid; i < R*64; i += 256){
        int n = base + i/64;
        ins[i] = (n < nN) ? in[(size_t)n*64 + (i & 63)] : 0.f;
    }
    __syncthreads();
    int r = tid / OUTC, c = tid % OUTC;
    int n = base + r;
    float acc = 0.f;
    #pragma unroll
    for (int d = 0; d < 64; ++d) acc += ins[r*64 + d] * Ws[d*OUTC + c];
    float ps = acc * asrc[c];
    float pd = acc * adst[c];
    #pragma unroll
    for (int m = 1; m <= 16; m <<= 1){ ps += __shfl_xor(ps, m); pd += __shfl_xor(pd, m); }
    float accN = __shfl_xor(acc, 1);   // neighbor channel (lane parity == c parity)
    if (n < nN){
        if ((c & 1) == 0){
            unsigned pk = rne_bf16(acc) | (rne_bf16(accN) << 16);
            hout2[(size_t)n*(OUTC/2) + (c >> 1)] = pk;
        }
        constexpr int HEADS = OUTC/32;
        if ((c & 31) == 0){
            int h = c >> 5;
            ssrc[n*HEADS + h] = ps;
            sdst[n*HEADS + h] = pd;
        }
    }
}

// ---------------- per-dst aggregation: EPI edges/iter, bf16x2 gather ----------------
// No max-subtraction (logits ~N(0,3), exp safe in fp32; softmax shift-invariant).
template<int OUTC>
__global__ void agg_kernel(const int* __restrict__ rowptr, const unsigned short* __restrict__ srcs,
                           const float* __restrict__ se0, const float* __restrict__ se1,
                           const float* __restrict__ ssrc, const float* __restrict__ sdst,
                           const unsigned* __restrict__ hbuf2, const float* __restrict__ bias,
                           float* __restrict__ outbuf, int nN){
    constexpr int HEADS = OUTC/32;
    constexpr int HALF  = OUTC/2;       // lanes per edge-subgroup
    constexpr int EPI   = 64/HALF;      // edges per inner iteration
    int wid = threadIdx.x >> 6;
    int lane = threadIdx.x & 63;
    int n = blockIdx.x*4 + wid;
    if (n >= nN) return;
    int row_start = rowptr[n], row_end = rowptr[n+1];
    int degn = row_end - row_start;
    float sd0 = sdst[n*HEADS + 0];
    float sd1 = (HEADS == 2) ? sdst[n*HEADS + 1] : 0.f;

    int sub = lane / HALF;              // which edge of the group this lane serves
    int lc  = lane & (HALF - 1);        // channel-pair index: channels 2lc, 2lc+1
    int h   = (HEADS == 2) ? (lc >> 4) : 0;

    float acc0 = 0.f, acc1 = 0.f, den = 0.f;
    float ssp0 = 0.f, ssp1 = 0.f;

    for (int p0 = row_start; p0 < row_end; p0 += 64){
        int myp = p0 + lane;
        int srcreg = 0; float w0 = 0.f, w1 = 0.f;
        if (myp < row_end){
            srcreg = srcs[myp];
            float e0 = se0[myp];
            ssp0 += e0;
            if (HEADS == 2){
                float2 sv = ((const float2*)ssrc)[srcreg];
                float e1 = se1[myp];
                ssp1 += e1;
                w0 = __expf(leaky(sv.x + sd0 + e0));
                w1 = __expf(leaky(sv.y + sd1 + e1));
            } else {
                w0 = __expf(leaky(ssrc[srcreg] + sd0 + e0));
            }
        }
        int cnt = min(64, row_end - p0);
        for (int q = sub; q < cnt; q += EPI){
            int sj = __shfl(srcreg, q);
            float wa = __shfl(w0, q);
            float wj;
            if (HEADS == 2){
                float wb = __shfl(w1, q);
                wj = h ? wb : wa;
            } else wj = wa;
            den += wj;
            unsigned hv = hbuf2[(size_t)sj*HALF + lc];
            acc0 += wj * __uint_as_float(hv << 16);
            acc1 += wj * __uint_as_float(hv & 0xFFFF0000u);
        }
    }

    // reduce partial sums across edge-subgroups (acc/den) and full wave (ssp)
    #pragma unroll
    for (int m = HALF; m < 64; m <<= 1){
        acc0 += __shfl_xor(acc0, m);
        acc1 += __shfl_xor(acc1, m);
        den  += __shfl_xor(den, m);
    }
    #pragma unroll
    for (int m = 1; m < 64; m <<= 1){
        ssp0 += __shfl_xor(ssp0, m);
        if (HEADS == 2) ssp1 += __shfl_xor(ssp1, m);
    }

    float invdeg = 1.f / (float)max(degn, 1);
    float srh = ssrc[n*HEADS + h];
    float sdh = h ? sd1 : sd0;
    float ssh = h ? ssp1 : ssp0;
    float wself = __expf(leaky(srh + sdh + ssh*invdeg));
    unsigned hv = hbuf2[(size_t)n*HALF + lc];
    acc0 += wself * __uint_as_float(hv << 16);
    acc1 += wself * __uint_as_float(hv & 0xFFFF0000u);
    den += wself;

    if (lane < HALF){
        float inv = 1.f / (den + 1e-16f);
        float o0 = fmaxf(acc0*inv + bias[2*lc], 0.f);
        float o1 = fmaxf(acc1*inv + bias[2*lc+1], 0.f);
        ((float2*)outbuf)[(size_t)n*HALF + lc] = make_float2(o0, o1);
    }
}

// ---------------- pooling + head ----------------
__global__ void pool_kernel(const float* __restrict__ h3, const int* __restrict__ batch,
                            float* __restrict__ pool, float* __restrict__ cnt, int nN){
    __shared__ float accs[GG*32];
    __shared__ float acccnt[GG];
    int tid = threadIdx.x;
    for (int i = tid; i < GG*32; i += 256) accs[i] = 0.f;
    if (tid < GG) acccnt[tid] = 0.f;
    __syncthreads();
    int r = tid >> 5, c = tid & 31;
    int base = blockIdx.x * 512;
    int end = min(base + 512, nN);
    for (int n = base + r; n < end; n += 8){
        int g = batch[n];
        atomicAdd(&accs[g*32 + c], h3[(size_t)n*32 + c]);
        if (c == 0) atomicAdd(&acccnt[g], 1.f);
    }
    __syncthreads();
    for (int i = tid; i < GG*32; i += 256) atomicAdd(&pool[i], accs[i]);
    if (tid < GG) atomicAdd(&cnt[tid], acccnt[tid]);
}

__global__ void final_kernel(const float* __restrict__ pool, const float* __restrict__ cnt,
                             const float* __restrict__ Wf, const float* __restrict__ bf,
                             float* __restrict__ out){
    int g = threadIdx.x;
    if (g >= GG) return;
    float ic = 1.f / fmaxf(cnt[g], 1.f);
    float lg[NCLS];
    #pragma unroll
    for (int k = 0; k < NCLS; ++k) lg[k] = bf[k];
    for (int c = 0; c < 32; ++c){
        float v = pool[g*32 + c] * ic;
        #pragma unroll
        for (int k = 0; k < NCLS; ++k) lg[k] += v * Wf[c*NCLS + k];
    }
    float mx = lg[0];
    #pragma unroll
    for (int k = 1; k < NCLS; ++k) mx = fmaxf(mx, lg[k]);
    float sum = 0.f, ex[NCLS];
    #pragma unroll
    for (int k = 0; k < NCLS; ++k){ ex[k] = expf(lg[k] - mx); sum += ex[k]; }
    #pragma unroll
    for (int k = 0; k < NCLS; ++k) out[g*NCLS + k] = ex[k]/sum;
}

extern "C" void kernel_launch(void* const* d_in, const int* in_sizes, int n_in,
                              void* d_out, int out_size, void* d_ws, size_t ws_size,
                              hipStream_t stream){
    const float* x     = (const float*)d_in[0];
    const int*   eidx  = (const int*)d_in[1];
    const float* eattr = (const float*)d_in[2];
    const int*   batch = (const int*)d_in[3];
    const float* W1 = (const float*)d_in[4];  const float* asrc1 = (const float*)d_in[5];
    const float* adst1 = (const float*)d_in[6]; const float* We1 = (const float*)d_in[7];
    const float* ae1 = (const float*)d_in[8];  const float* b1 = (const float*)d_in[9];
    const float* W2 = (const float*)d_in[10]; const float* asrc2 = (const float*)d_in[11];
    const float* adst2 = (const float*)d_in[12]; const float* We2 = (const float*)d_in[13];
    const float* ae2 = (const float*)d_in[14]; const float* b2 = (const float*)d_in[15];
    const float* W3 = (const float*)d_in[16]; const float* asrc3 = (const float*)d_in[17];
    const float* adst3 = (const float*)d_in[18]; const float* We3 = (const float*)d_in[19];
    const float* ae3 = (const float*)d_in[20]; const float* b3 = (const float*)d_in[21];
    const float* Wf = (const float*)d_in[22]; const float* bf = (const float*)d_in[23];
    float* out = (float*)d_out;

    char* ws = (char*)d_ws;
    int*   deg    = (int*)(ws + OFF_DEG);
    int*   rowptr = (int*)(ws + OFF_ROWPTR);
    int*   curs   = (int*)(ws + OFF_CURSOR);
    unsigned short* srcs = (unsigned short*)(ws + OFF_CSR);
    int*   eidA   = (int*)(ws + OFF_EID);
    float* se     = (float*)(ws + OFF_SE);
    float* ssrc   = (float*)(ws + OFF_SSRC);
    float* sdst   = (float*)(ws + OFF_SDST);
    unsigned* bufH = (unsigned*)(ws + OFF_BUFH);
    float* bufO   = (float*)(ws + OFF_BUFO);
    float* weff   = (float*)(ws + OFF_WEFF);
    float* pool   = (float*)(ws + OFF_POOL);
    float* cnt    = pool + GG*32;

    int* bincursor = curs;
    int* bsum      = curs + 512;
    int* boff      = curs + 1024;
    int2* staging  = (int2*)bufH;   // bufH dead until transforms; 10MB <= 12.8MB

    const int* srcA = eidx;
    const int* dstA = eidx + EE;

    hipMemsetAsync(deg, 0, (size_t)NN*4, stream);
    hipMemsetAsync(pool, 0, (GG*32 + GG)*4, stream);

    int egrid = (EE + 255)/256;
    deg_kernel<<<egrid, 256, 0, stream>>>(dstA, deg, EE);
    int sgrid = (NN + 1023)/1024;  // 49
    bsum_kernel<<<sgrid, 1024, 0, stream>>>(deg, bsum, NN);
    bscan_kernel<<<1, 64, 0, stream>>>(bsum, boff, rowptr, sgrid, NN);
    wptr_kernel<<<sgrid, 1024, 0, stream>>>(deg, boff, rowptr, NN);
    binit_kernel<<<(NBIN+255)/256, 256, 0, stream>>>(rowptr, bincursor);
    binA_kernel<<<(EE + 8191)/8192, 1024, 0, stream>>>(srcA, dstA, bincursor, staging, EE);
    binB_kernel<<<NBIN, 1024, 0, stream>>>(rowptr, staging, srcs, eidA, NN);

    weff_kernel<<<1, 128, 0, stream>>>(We1, ae1, We2, ae2, We3, ae3, weff);
    se_kernel<<<egrid, 256, 0, stream>>>(eidA, eattr, weff, se, EE);

    int ngrid4 = (NN + 3)/4;
    int ngrid8 = (NN + 7)/8;
    // layer 1
    transform_kernel<64><<<ngrid4, 256, 0, stream>>>(x, W1, asrc1, adst1, bufH, ssrc, sdst, NN);
    agg_kernel<64><<<ngrid4, 256, 0, stream>>>(rowptr, srcs, se + 0*(size_t)EE, se + 1*(size_t)EE,
                                               ssrc, sdst, bufH, b1, bufO, NN);
    // layer 2
    transform_kernel<64><<<ngrid4, 256, 0, stream>>>(bufO, W2, asrc2, adst2, bufH, ssrc, sdst, NN);
    agg_kernel<64><<<ngrid4, 256, 0, stream>>>(rowptr, srcs, se + 2*(size_t)EE, se + 3*(size_t)EE,
                                               ssrc, sdst, bufH, b2, bufO, NN);
    // layer 3 (1 head, 32 out, concat=False -> mean over 1 head = identity)
    transform_kernel<32><<<ngrid8, 256, 0, stream>>>(bufO, W3, asrc3, adst3, bufH, ssrc, sdst, NN);
    agg_kernel<32><<<ngrid4, 256, 0, stream>>>(rowptr, srcs, se + 4*(size_t)EE, nullptr,
                                               ssrc, sdst, bufH, b3, bufO, NN);
    // pool + ffn + softmax
    pool_kernel<<<(NN + 511)/512, 256, 0, stream>>>(bufO, batch, pool, cnt, NN);
    final_kernel<<<1, 64, 0, stream>>>(pool, cnt, Wf, bf, out);
}

// Round 5
// 325.301 us; speedup vs baseline: 1.9913x; 1.1557x over previous
//
#include <hip/hip_runtime.h>
#include <math.h>

#define NN 50000
#define EE 1250000
#define GG 16
#define NCLS 5
#define NBIN 391        // ceil(50000 / 128)
#define BINSHIFT 7
#define CAPB 3900       // max edges per bin (mean 3200, sigma ~57 -> 12 sigma headroom)

constexpr size_t AL(size_t x){ return (x + 255) & ~size_t(255); }
constexpr size_t OFF_DEG    = 0;
constexpr size_t OFF_ROWPTR = OFF_DEG + AL((size_t)NN*4);
constexpr size_t OFF_CURSOR = OFF_ROWPTR + AL((size_t)(NN+1)*4);   // bincursor/bsum/boff
constexpr size_t OFF_CSR    = OFF_CURSOR + AL((size_t)NN*4);       // srcs(ushort E) + eid(int E)
constexpr size_t OFF_EID    = OFF_CSR + AL((size_t)EE*2);
constexpr size_t OFF_SE     = OFF_CSR + AL((size_t)EE*8);
constexpr size_t OFF_SSRC   = OFF_SE + AL((size_t)EE*5*4);
constexpr size_t OFF_SDST   = OFF_SSRC + AL((size_t)NN*2*4);
constexpr size_t OFF_BUFH   = OFF_SDST + AL((size_t)NN*2*4);       // bf16x2 h; also bin staging
constexpr size_t OFF_BUFO   = OFF_BUFH + AL((size_t)NN*64*4);
constexpr size_t OFF_WEFF   = OFF_BUFO + AL((size_t)NN*64*4);
constexpr size_t OFF_POOL   = OFF_WEFF + AL(80*4);

__device__ __forceinline__ float leaky(float x){ return x > 0.f ? x : 0.2f*x; }
__device__ __forceinline__ unsigned rne_bf16(float x){
    unsigned u = __float_as_uint(x);
    return (u + 0x7FFFu + ((u >> 16) & 1u)) >> 16;
}

// ---------------- CSR build (no global atomics on deg) ----------------
__global__ void binit_kernel(int* __restrict__ bincursor){
    int b = blockIdx.x*256 + threadIdx.x;
    if (b < NBIN) bincursor[b] = b*CAPB;
}

// pass A: bin edges by dst>>7 into fixed-capacity regions, time-local dense writes
__global__ void binA_kernel(const int* __restrict__ src, const int* __restrict__ dst,
                            int* __restrict__ bincursor, int2* __restrict__ staging, int nE){
    __shared__ int lcount[NBIN];
    __shared__ int lbase[NBIN];
    int tid = threadIdx.x;  // 1024
    for (int i = tid; i < NBIN; i += 1024) lcount[i] = 0;
    __syncthreads();
    int base = blockIdx.x * 8192;
    int w0[8], eid[8], bn[8], idx[8];
    #pragma unroll
    for (int k = 0; k < 8; ++k){
        int i = base + k*1024 + tid;
        if (i < nE){
            int d = dst[i];
            int s = src[i];                   // < 65536, fits 16 bits
            bn[k]  = d >> BINSHIFT;
            w0[k]  = s | ((d & 127) << 16);
            eid[k] = i;
            idx[k] = atomicAdd(&lcount[bn[k]], 1);
        } else bn[k] = -1;
    }
    __syncthreads();
    for (int i = tid; i < NBIN; i += 1024)
        lbase[i] = atomicAdd(&bincursor[i], lcount[i]);
    __syncthreads();
    #pragma unroll
    for (int k = 0; k < 8; ++k)
        if (bn[k] >= 0)
            staging[lbase[bn[k]] + idx[k]] = make_int2(w0[k], eid[k]);
}

// per-bin LDS histogram -> coalesced deg writes (replaces 1.25M global atomics)
__global__ void hist_kernel(const int2* __restrict__ staging, const int* __restrict__ bincursor,
                            int* __restrict__ deg, int nN){
    __shared__ int lcnt[128];
    int b = blockIdx.x;
    int tid = threadIdx.x;  // 256
    if (tid < 128) lcnt[tid] = 0;
    __syncthreads();
    int base = b*CAPB;
    int cnt = bincursor[b] - base;
    for (int k = tid; k < cnt; k += 256)
        atomicAdd(&lcnt[staging[base + k].x >> 16], 1);
    __syncthreads();
    int lo = b << BINSHIFT;
    if (tid < 128 && lo + tid < nN) deg[lo + tid] = lcnt[tid];
}

__global__ void bsum_kernel(const int* __restrict__ deg, int* __restrict__ bsum, int nN){
    __shared__ int s[1024];
    int tid = threadIdx.x;
    int i = blockIdx.x*1024 + tid;
    s[tid] = (i < nN) ? deg[i] : 0;
    __syncthreads();
    for (int off = 512; off > 0; off >>= 1){
        if (tid < off) s[tid] += s[tid+off];
        __syncthreads();
    }
    if (tid == 0) bsum[blockIdx.x] = s[0];
}

__global__ void bscan_kernel(const int* __restrict__ bsum, int* __restrict__ boff,
                             int* __restrict__ rowptr, int nB, int nN){
    int lane = threadIdx.x;  // 64
    int v = (lane < nB) ? bsum[lane] : 0;
    int incl = v;
    #pragma unroll
    for (int off = 1; off < 64; off <<= 1){
        int t = __shfl_up(incl, off);
        if (lane >= off) incl += t;
    }
    if (lane < nB) boff[lane] = incl - v;
    if (lane == 63) rowptr[nN] = incl;
}

__global__ void wptr_kernel(const int* __restrict__ deg, const int* __restrict__ boff,
                            int* __restrict__ rowptr, int nN){
    __shared__ int s[1024];
    int tid = threadIdx.x;
    int i = blockIdx.x*1024 + tid;
    int v = (i < nN) ? deg[i] : 0;
    s[tid] = v;
    __syncthreads();
    for (int off = 1; off < 1024; off <<= 1){
        int t = (tid >= off) ? s[tid-off] : 0;
        __syncthreads();
        s[tid] += t;
        __syncthreads();
    }
    if (i < nN) rowptr[i] = boff[blockIdx.x] + s[tid] - v;
}

// pass B: per-bin LDS reorder -> srcs (ushort) + eid (int), coalesced writes
__global__ void binB_kernel(const int* __restrict__ rowptr, const int2* __restrict__ staging,
                            unsigned short* __restrict__ srcs, int* __restrict__ eidA, int nN){
    __shared__ int2 lin[CAPB];
    __shared__ int2 lout[CAPB];
    __shared__ int lcnt[128];
    int b = blockIdx.x;
    int lo = b << BINSHIFT;
    int hi = min(lo + 128, nN);
    int r0 = rowptr[lo], r1 = rowptr[hi];
    int cnt = r1 - r0;
    int sbase = b*CAPB;
    int tid = threadIdx.x;  // 1024
    if (tid < 128) lcnt[tid] = 0;
    for (int k = tid; k < cnt && k < CAPB; k += 1024) lin[k] = staging[sbase + k];
    __syncthreads();
    for (int k = tid; k < cnt; k += 1024){
        int2 v = (k < CAPB) ? lin[k] : staging[sbase + k];
        int dl = v.x >> 16;
        int rank = atomicAdd(&lcnt[dl], 1);
        int target = rowptr[lo + dl] - r0 + rank;
        int2 outv = make_int2(v.x & 0xFFFF, v.y);
        if (target < CAPB) lout[target] = outv;
        else { srcs[r0 + target] = (unsigned short)outv.x; eidA[r0 + target] = outv.y; }
    }
    __syncthreads();
    int m = min(cnt, CAPB);
    for (int k = tid; k < m; k += 1024){
        srcs[r0 + k] = (unsigned short)lout[k].x;
        eidA[r0 + k] = lout[k].y;
    }
}

// ---------------- edge score precompute ----------------
__global__ void weff_kernel(const float* __restrict__ We1, const float* __restrict__ ae1,
                            const float* __restrict__ We2, const float* __restrict__ ae2,
                            const float* __restrict__ We3, const float* __restrict__ ae3,
                            float* __restrict__ weff){
    int t = threadIdx.x;
    if (t >= 80) return;
    int j = t >> 4, d = t & 15;
    const float* We; const float* ae; int hc, h;
    if (j == 0){ We = We1; ae = ae1; hc = 64; h = 0; }
    else if (j == 1){ We = We1; ae = ae1; hc = 64; h = 1; }
    else if (j == 2){ We = We2; ae = ae2; hc = 64; h = 0; }
    else if (j == 3){ We = We2; ae = ae2; hc = 64; h = 1; }
    else { We = We3; ae = ae3; hc = 32; h = 0; }
    float s = 0.f;
    for (int c = 0; c < 32; ++c) s += We[d*hc + h*32 + c] * ae[h*32 + c];
    weff[j*16 + d] = s;
}

__global__ void se_kernel(const int* __restrict__ eidA, const float* __restrict__ eattr,
                          const float* __restrict__ weff, float* __restrict__ se, int nE){
    __shared__ float w[80];
    int tid = threadIdx.x;
    if (tid < 80) w[tid] = weff[tid];
    __syncthreads();
    int p = blockIdx.x*256 + tid;
    if (p >= nE) return;
    int e = eidA[p];
    const float4* row = (const float4*)(eattr + (size_t)e*16);
    float4 a0 = row[0], a1 = row[1], a2 = row[2], a3 = row[3];
    float a[16] = {a0.x,a0.y,a0.z,a0.w, a1.x,a1.y,a1.z,a1.w,
                   a2.x,a2.y,a2.z,a2.w, a3.x,a3.y,a3.z,a3.w};
    #pragma unroll
    for (int j = 0; j < 5; ++j){
        float s = 0.f;
        #pragma unroll
        for (int d = 0; d < 16; ++d) s += a[d]*w[j*16+d];
        se[(size_t)j*nE + p] = s;
    }
}

// ---------------- node transform: h = in @ W (bf16x2 packed out); s_src/s_dst fused ----
template<int OUTC>
__global__ void transform_kernel(const float* __restrict__ in, const float* __restrict__ W,
                                 const float* __restrict__ asrc, const float* __restrict__ adst,
                                 unsigned* __restrict__ hout2, float* __restrict__ ssrc,
                                 float* __restrict__ sdst, int nN){
    constexpr int R = 256/OUTC;
    __shared__ float Ws[64*OUTC];
    __shared__ float ins[R*64];
    int tid = threadIdx.x;
    for (int i = tid; i < 64*OUTC; i += 256) Ws[i] = W[i];
    int base = blockIdx.x * R;
    for (int i = tid; i < R*64; i += 256){
        int n = base + i/64;
        ins[i] = (n < nN) ? in[(size_t)n*64 + (i & 63)] : 0.f;
    }
    __syncthreads();
    int r = tid / OUTC, c = tid % OUTC;
    int n = base + r;
    float acc = 0.f;
    #pragma unroll
    for (int d = 0; d < 64; ++d) acc += ins[r*64 + d] * Ws[d*OUTC + c];
    float ps = acc * asrc[c];
    float pd = acc * adst[c];
    #pragma unroll
    for (int m = 1; m <= 16; m <<= 1){ ps += __shfl_xor(ps, m); pd += __shfl_xor(pd, m); }
    float accN = __shfl_xor(acc, 1);   // neighbor channel (lane parity == c parity)
    if (n < nN){
        if ((c & 1) == 0){
            unsigned pk = rne_bf16(acc) | (rne_bf16(accN) << 16);
            hout2[(size_t)n*(OUTC/2) + (c >> 1)] = pk;
        }
        constexpr int HEADS = OUTC/32;
        if ((c & 31) == 0){
            int h = c >> 5;
            ssrc[n*HEADS + h] = ps;
            sdst[n*HEADS + h] = pd;
        }
    }
}

// ---------------- per-dst aggregation: EPI edges/iter, bf16x2 gather ----------------
// No max-subtraction (logits ~N(0,3), exp safe in fp32; softmax shift-invariant).
template<int OUTC>
__global__ void agg_kernel(const int* __restrict__ rowptr, const unsigned short* __restrict__ srcs,
                           const float* __restrict__ se0, const float* __restrict__ se1,
                           const float* __restrict__ ssrc, const float* __restrict__ sdst,
                           const unsigned* __restrict__ hbuf2, const float* __restrict__ bias,
                           float* __restrict__ outbuf, int nN){
    constexpr int HEADS = OUTC/32;
    constexpr int HALF  = OUTC/2;       // lanes per edge-subgroup
    constexpr int EPI   = 64/HALF;      // edges per inner iteration
    int wid = threadIdx.x >> 6;
    int lane = threadIdx.x & 63;
    int n = blockIdx.x*4 + wid;
    if (n >= nN) return;
    int row_start = rowptr[n], row_end = rowptr[n+1];
    int degn = row_end - row_start;
    float sd0 = sdst[n*HEADS + 0];
    float sd1 = (HEADS == 2) ? sdst[n*HEADS + 1] : 0.f;

    int sub = lane / HALF;              // which edge of the group this lane serves
    int lc  = lane & (HALF - 1);        // channel-pair index: channels 2lc, 2lc+1
    int h   = (HEADS == 2) ? (lc >> 4) : 0;

    float acc0 = 0.f, acc1 = 0.f, den = 0.f;
    float ssp0 = 0.f, ssp1 = 0.f;

    for (int p0 = row_start; p0 < row_end; p0 += 64){
        int myp = p0 + lane;
        int srcreg = 0; float w0 = 0.f, w1 = 0.f;
        if (myp < row_end){
            srcreg = srcs[myp];
            float e0 = se0[myp];
            ssp0 += e0;
            if (HEADS == 2){
                float2 sv = ((const float2*)ssrc)[srcreg];
                float e1 = se1[myp];
                ssp1 += e1;
                w0 = __expf(leaky(sv.x + sd0 + e0));
                w1 = __expf(leaky(sv.y + sd1 + e1));
            } else {
                w0 = __expf(leaky(ssrc[srcreg] + sd0 + e0));
            }
        }
        int cnt = min(64, row_end - p0);
        for (int q = sub; q < cnt; q += EPI){
            int sj = __shfl(srcreg, q);
            float wa = __shfl(w0, q);
            float wj;
            if (HEADS == 2){
                float wb = __shfl(w1, q);
                wj = h ? wb : wa;
            } else wj = wa;
            den += wj;
            unsigned hv = hbuf2[(size_t)sj*HALF + lc];
            acc0 += wj * __uint_as_float(hv << 16);
            acc1 += wj * __uint_as_float(hv & 0xFFFF0000u);
        }
    }

    // reduce partial sums across edge-subgroups (acc/den) and full wave (ssp)
    #pragma unroll
    for (int m = HALF; m < 64; m <<= 1){
        acc0 += __shfl_xor(acc0, m);
        acc1 += __shfl_xor(acc1, m);
        den  += __shfl_xor(den, m);
    }
    #pragma unroll
    for (int m = 1; m < 64; m <<= 1){
        ssp0 += __shfl_xor(ssp0, m);
        if (HEADS == 2) ssp1 += __shfl_xor(ssp1, m);
    }

    float invdeg = 1.f / (float)max(degn, 1);
    float srh = ssrc[n*HEADS + h];
    float sdh = h ? sd1 : sd0;
    float ssh = h ? ssp1 : ssp0;
    float wself = __expf(leaky(srh + sdh + ssh*invdeg));
    unsigned hv = hbuf2[(size_t)n*HALF + lc];
    acc0 += wself * __uint_as_float(hv << 16);
    acc1 += wself * __uint_as_float(hv & 0xFFFF0000u);
    den += wself;

    if (lane < HALF){
        float inv = 1.f / (den + 1e-16f);
        float o0 = fmaxf(acc0*inv + bias[2*lc], 0.f);
        float o1 = fmaxf(acc1*inv + bias[2*lc+1], 0.f);
        ((float2*)outbuf)[(size_t)n*HALF + lc] = make_float2(o0, o1);
    }
}

// ---------------- pooling + head ----------------
__global__ void pool_kernel(const float* __restrict__ h3, const int* __restrict__ batch,
                            float* __restrict__ pool, float* __restrict__ cnt, int nN){
    __shared__ float accs[GG*32];
    __shared__ float acccnt[GG];
    int tid = threadIdx.x;
    for (int i = tid; i < GG*32; i += 256) accs[i] = 0.f;
    if (tid < GG) acccnt[tid] = 0.f;
    __syncthreads();
    int r = tid >> 5, c = tid & 31;
    int base = blockIdx.x * 512;
    int end = min(base + 512, nN);
    for (int n = base + r; n < end; n += 8){
        int g = batch[n];
        atomicAdd(&accs[g*32 + c], h3[(size_t)n*32 + c]);
        if (c == 0) atomicAdd(&acccnt[g], 1.f);
    }
    __syncthreads();
    for (int i = tid; i < GG*32; i += 256) atomicAdd(&pool[i], accs[i]);
    if (tid < GG) atomicAdd(&cnt[tid], acccnt[tid]);
}

__global__ void final_kernel(const float* __restrict__ pool, const float* __restrict__ cnt,
                             const float* __restrict__ Wf, const float* __restrict__ bf,
                             float* __restrict__ out){
    int g = threadIdx.x;
    if (g >= GG) return;
    float ic = 1.f / fmaxf(cnt[g], 1.f);
    float lg[NCLS];
    #pragma unroll
    for (int k = 0; k < NCLS; ++k) lg[k] = bf[k];
    for (int c = 0; c < 32; ++c){
        float v = pool[g*32 + c] * ic;
        #pragma unroll
        for (int k = 0; k < NCLS; ++k) lg[k] += v * Wf[c*NCLS + k];
    }
    float mx = lg[0];
    #pragma unroll
    for (int k = 1; k < NCLS; ++k) mx = fmaxf(mx, lg[k]);
    float sum = 0.f, ex[NCLS];
    #pragma unroll
    for (int k = 0; k < NCLS; ++k){ ex[k] = expf(lg[k] - mx); sum += ex[k]; }
    #pragma unroll
    for (int k = 0; k < NCLS; ++k) out[g*NCLS + k] = ex[k]/sum;
}

extern "C" void kernel_launch(void* const* d_in, const int* in_sizes, int n_in,
                              void* d_out, int out_size, void* d_ws, size_t ws_size,
                              hipStream_t stream){
    const float* x     = (const float*)d_in[0];
    const int*   eidx  = (const int*)d_in[1];
    const float* eattr = (const float*)d_in[2];
    const int*   batch = (const int*)d_in[3];
    const float* W1 = (const float*)d_in[4];  const float* asrc1 = (const float*)d_in[5];
    const float* adst1 = (const float*)d_in[6]; const float* We1 = (const float*)d_in[7];
    const float* ae1 = (const float*)d_in[8];  const float* b1 = (const float*)d_in[9];
    const float* W2 = (const float*)d_in[10]; const float* asrc2 = (const float*)d_in[11];
    const float* adst2 = (const float*)d_in[12]; const float* We2 = (const float*)d_in[13];
    const float* ae2 = (const float*)d_in[14]; const float* b2 = (const float*)d_in[15];
    const float* W3 = (const float*)d_in[16]; const float* asrc3 = (const float*)d_in[17];
    const float* adst3 = (const float*)d_in[18]; const float* We3 = (const float*)d_in[19];
    const float* ae3 = (const float*)d_in[20]; const float* b3 = (const float*)d_in[21];
    const float* Wf = (const float*)d_in[22]; const float* bf = (const float*)d_in[23];
    float* out = (float*)d_out;

    char* ws = (char*)d_ws;
    int*   deg    = (int*)(ws + OFF_DEG);
    int*   rowptr = (int*)(ws + OFF_ROWPTR);
    int*   curs   = (int*)(ws + OFF_CURSOR);
    unsigned short* srcs = (unsigned short*)(ws + OFF_CSR);
    int*   eidA   = (int*)(ws + OFF_EID);
    float* se     = (float*)(ws + OFF_SE);
    float* ssrc   = (float*)(ws + OFF_SSRC);
    float* sdst   = (float*)(ws + OFF_SDST);
    unsigned* bufH = (unsigned*)(ws + OFF_BUFH);
    float* bufO   = (float*)(ws + OFF_BUFO);
    float* weff   = (float*)(ws + OFF_WEFF);
    float* pool   = (float*)(ws + OFF_POOL);
    float* cnt    = pool + GG*32;

    int* bincursor = curs;
    int* bsum      = curs + 512;
    int* boff      = curs + 1024;
    int2* staging  = (int2*)bufH;   // bufH dead until transforms; NBIN*CAPB*8 = 12.2MB <= 12.8MB

    const int* srcA = eidx;
    const int* dstA = eidx + EE;

    hipMemsetAsync(pool, 0, (GG*32 + GG)*4, stream);

    // CSR build: bin first (fixed-capacity regions), histogram from bins, scan, reorder
    binit_kernel<<<(NBIN+255)/256, 256, 0, stream>>>(bincursor);
    binA_kernel<<<(EE + 8191)/8192, 1024, 0, stream>>>(srcA, dstA, bincursor, staging, EE);
    hist_kernel<<<NBIN, 256, 0, stream>>>(staging, bincursor, deg, NN);
    int sgrid = (NN + 1023)/1024;  // 49
    bsum_kernel<<<sgrid, 1024, 0, stream>>>(deg, bsum, NN);
    bscan_kernel<<<1, 64, 0, stream>>>(bsum, boff, rowptr, sgrid, NN);
    wptr_kernel<<<sgrid, 1024, 0, stream>>>(deg, boff, rowptr, NN);
    binB_kernel<<<NBIN, 1024, 0, stream>>>(rowptr, staging, srcs, eidA, NN);

    weff_kernel<<<1, 128, 0, stream>>>(We1, ae1, We2, ae2, We3, ae3, weff);
    int egrid = (EE + 255)/256;
    se_kernel<<<egrid, 256, 0, stream>>>(eidA, eattr, weff, se, EE);

    int ngrid4 = (NN + 3)/4;
    int ngrid8 = (NN + 7)/8;
    // layer 1
    transform_kernel<64><<<ngrid4, 256, 0, stream>>>(x, W1, asrc1, adst1, bufH, ssrc, sdst, NN);
    agg_kernel<64><<<ngrid4, 256, 0, stream>>>(rowptr, srcs, se + 0*(size_t)EE, se + 1*(size_t)EE,
                                               ssrc, sdst, bufH, b1, bufO, NN);
    // layer 2
    transform_kernel<64><<<ngrid4, 256, 0, stream>>>(bufO, W2, asrc2, adst2, bufH, ssrc, sdst, NN);
    agg_kernel<64><<<ngrid4, 256, 0, stream>>>(rowptr, srcs, se + 2*(size_t)EE, se + 3*(size_t)EE,
                                               ssrc, sdst, bufH, b2, bufO, NN);
    // layer 3 (1 head, 32 out, concat=False -> mean over 1 head = identity)
    transform_kernel<32><<<ngrid8, 256, 0, stream>>>(bufO, W3, asrc3, adst3, bufH, ssrc, sdst, NN);
    agg_kernel<32><<<ngrid4, 256, 0, stream>>>(rowptr, srcs, se + 4*(size_t)EE, nullptr,
                                               ssrc, sdst, bufH, b3, bufO, NN);
    // pool + ffn + softmax
    pool_kernel<<<(NN + 511)/512, 256, 0, stream>>>(bufO, batch, pool, cnt, NN);
    final_kernel<<<1, 64, 0, stream>>>(pool, cnt, Wf, bf, out);
}

// Round 6
// 274.396 us; speedup vs baseline: 2.3608x; 1.1855x over previous
//
#include <hip/hip_runtime.h>
#include <math.h>

#define NN 50000
#define EE 1250000
#define GG 16
#define NCLS 5
#define NBIN 391        // ceil(50000 / 128)
#define BINSHIFT 7
#define CAPB 3900       // max edges per bin (mean 3200, sigma ~57 -> 12 sigma headroom)

constexpr size_t AL(size_t x){ return (x + 255) & ~size_t(255); }
constexpr size_t OFF_DEG    = 0;
constexpr size_t OFF_ROWPTR = OFF_DEG + AL((size_t)NN*4);
constexpr size_t OFF_CURSOR = OFF_ROWPTR + AL((size_t)(NN+1)*4);   // bincursor/bsum/boff
constexpr size_t OFF_SRCS   = OFF_CURSOR + AL((size_t)NN*4);
constexpr size_t OFF_SE12   = OFF_SRCS + AL((size_t)EE*2);
constexpr size_t OFF_SE34   = OFF_SE12 + AL((size_t)EE*4);
constexpr size_t OFF_SE5    = OFF_SE34 + AL((size_t)EE*4);
constexpr size_t OFF_SSRC   = OFF_SE5 + AL((size_t)EE*2);
constexpr size_t OFF_SDST   = OFF_SSRC + AL((size_t)NN*2*4);
constexpr size_t OFF_STAG   = OFF_SDST + AL((size_t)NN*2*4);
constexpr size_t OFF_BUFH   = OFF_STAG + AL((size_t)NBIN*CAPB*16);
constexpr size_t OFF_BUFO   = OFF_BUFH + AL((size_t)NN*32*4);      // bf16x2 h (max 32 u32/node)
constexpr size_t OFF_WEFF   = OFF_BUFO + AL((size_t)NN*64*4);
constexpr size_t OFF_POOL   = OFF_WEFF + AL(80*4);

__device__ __forceinline__ float leaky(float x){ return x > 0.f ? x : 0.2f*x; }
__device__ __forceinline__ unsigned rne_bf16(float x){
    unsigned u = __float_as_uint(x);
    return (u + 0x7FFFu + ((u >> 16) & 1u)) >> 16;
}

// ---------------- weff: fold We,ae into 16-dim vectors (5 head-layers) ----------------
__global__ void weff_kernel(const float* __restrict__ We1, const float* __restrict__ ae1,
                            const float* __restrict__ We2, const float* __restrict__ ae2,
                            const float* __restrict__ We3, const float* __restrict__ ae3,
                            float* __restrict__ weff){
    int t = threadIdx.x;
    if (t >= 80) return;
    int j = t >> 4, d = t & 15;
    const float* We; const float* ae; int hc, h;
    if (j == 0){ We = We1; ae = ae1; hc = 64; h = 0; }
    else if (j == 1){ We = We1; ae = ae1; hc = 64; h = 1; }
    else if (j == 2){ We = We2; ae = ae2; hc = 64; h = 0; }
    else if (j == 3){ We = We2; ae = ae2; hc = 64; h = 1; }
    else { We = We3; ae = ae3; hc = 32; h = 0; }
    float s = 0.f;
    for (int c = 0; c < 32; ++c) s += We[d*hc + h*32 + c] * ae[h*32 + c];
    weff[j*16 + d] = s;
}

// ---------------- CSR build ----------------
__global__ void binit_kernel(int* __restrict__ bincursor){
    int b = blockIdx.x*256 + threadIdx.x;
    if (b < NBIN) bincursor[b] = b*CAPB;
}

// pass A: bin edges by dst>>7 into fixed-capacity regions; se computed inline
// (eattr read coalesced in ORIGINAL edge order, carried bf16-packed in staging)
__global__ void binA_kernel(const int* __restrict__ src, const int* __restrict__ dst,
                            const float* __restrict__ eattr, const float* __restrict__ weff,
                            int* __restrict__ bincursor, int4* __restrict__ staging, int nE){
    __shared__ int lcount[NBIN];
    __shared__ int lbase[NBIN];
    __shared__ float w[80];
    int tid = threadIdx.x;  // 1024
    if (tid < 80) w[tid] = weff[tid];
    for (int i = tid; i < NBIN; i += 1024) lcount[i] = 0;
    __syncthreads();
    int base = blockIdx.x * 8192;
    int w0[8], bn[8], idx[8]; unsigned p01[8], p23[8], p4[8];
    #pragma unroll
    for (int k = 0; k < 8; ++k){
        int i = base + k*1024 + tid;
        if (i < nE){
            int d = dst[i];
            int s = src[i];                   // < 65536, fits 16 bits
            bn[k]  = d >> BINSHIFT;
            w0[k]  = s | ((d & 127) << 16);
            const float4* row = (const float4*)(eattr + (size_t)i*16);
            float4 a0 = row[0], a1 = row[1], a2 = row[2], a3 = row[3];
            float a[16] = {a0.x,a0.y,a0.z,a0.w, a1.x,a1.y,a1.z,a1.w,
                           a2.x,a2.y,a2.z,a2.w, a3.x,a3.y,a3.z,a3.w};
            float sj[5];
            #pragma unroll
            for (int j = 0; j < 5; ++j){
                float s2 = 0.f;
                #pragma unroll
                for (int d2 = 0; d2 < 16; ++d2) s2 += a[d2]*w[j*16+d2];
                sj[j] = s2;
            }
            p01[k] = rne_bf16(sj[0]) | (rne_bf16(sj[1]) << 16);
            p23[k] = rne_bf16(sj[2]) | (rne_bf16(sj[3]) << 16);
            p4[k]  = rne_bf16(sj[4]);
            idx[k] = atomicAdd(&lcount[bn[k]], 1);
        } else bn[k] = -1;
    }
    __syncthreads();
    for (int i = tid; i < NBIN; i += 1024)
        lbase[i] = atomicAdd(&bincursor[i], lcount[i]);
    __syncthreads();
    #pragma unroll
    for (int k = 0; k < 8; ++k)
        if (bn[k] >= 0)
            staging[lbase[bn[k]] + idx[k]] = make_int4(w0[k], (int)p01[k], (int)p23[k], (int)p4[k]);
}

// per-bin LDS histogram -> coalesced deg writes
__global__ void hist_kernel(const int4* __restrict__ staging, const int* __restrict__ bincursor,
                            int* __restrict__ deg, int nN){
    __shared__ int lcnt[128];
    int b = blockIdx.x;
    int tid = threadIdx.x;  // 256
    if (tid < 128) lcnt[tid] = 0;
    __syncthreads();
    int base = b*CAPB;
    int cnt = bincursor[b] - base;
    for (int k = tid; k < cnt; k += 256)
        atomicAdd(&lcnt[staging[base + k].x >> 16], 1);
    __syncthreads();
    int lo = b << BINSHIFT;
    if (tid < 128 && lo + tid < nN) deg[lo + tid] = lcnt[tid];
}

__global__ void bsum_kernel(const int* __restrict__ deg, int* __restrict__ bsum, int nN){
    __shared__ int s[1024];
    int tid = threadIdx.x;
    int i = blockIdx.x*1024 + tid;
    s[tid] = (i < nN) ? deg[i] : 0;
    __syncthreads();
    for (int off = 512; off > 0; off >>= 1){
        if (tid < off) s[tid] += s[tid+off];
        __syncthreads();
    }
    if (tid == 0) bsum[blockIdx.x] = s[0];
}

__global__ void bscan_kernel(const int* __restrict__ bsum, int* __restrict__ boff,
                             int* __restrict__ rowptr, int nB, int nN){
    int lane = threadIdx.x;  // 64
    int v = (lane < nB) ? bsum[lane] : 0;
    int incl = v;
    #pragma unroll
    for (int off = 1; off < 64; off <<= 1){
        int t = __shfl_up(incl, off);
        if (lane >= off) incl += t;
    }
    if (lane < nB) boff[lane] = incl - v;
    if (lane == 63) rowptr[nN] = incl;
}

__global__ void wptr_kernel(const int* __restrict__ deg, const int* __restrict__ boff,
                            int* __restrict__ rowptr, int nN){
    __shared__ int s[1024];
    int tid = threadIdx.x;
    int i = blockIdx.x*1024 + tid;
    int v = (i < nN) ? deg[i] : 0;
    s[tid] = v;
    __syncthreads();
    for (int off = 1; off < 1024; off <<= 1){
        int t = (tid >= off) ? s[tid-off] : 0;
        __syncthreads();
        s[tid] += t;
        __syncthreads();
    }
    if (i < nN) rowptr[i] = boff[blockIdx.x] + s[tid] - v;
}

// pass B: one global read -> LDS scatter by dst-rank -> coalesced SoA writes
__global__ void binB_kernel(const int* __restrict__ rowptr, const int4* __restrict__ staging,
                            unsigned short* __restrict__ srcs, unsigned* __restrict__ se12,
                            unsigned* __restrict__ se34, unsigned short* __restrict__ se5, int nN){
    __shared__ int4 lout[CAPB];
    __shared__ int lcnt[128];
    int b = blockIdx.x;
    int lo = b << BINSHIFT;
    int hi = min(lo + 128, nN);
    int r0 = rowptr[lo], r1 = rowptr[hi];
    int cnt = r1 - r0;
    int sbase = b*CAPB;
    int tid = threadIdx.x;  // 1024
    if (tid < 128) lcnt[tid] = 0;
    __syncthreads();
    for (int k = tid; k < cnt; k += 1024){
        int4 v = staging[sbase + k];
        int dl = v.x >> 16;
        int rank = atomicAdd(&lcnt[dl], 1);
        int target = rowptr[lo + dl] - r0 + rank;
        v.x &= 0xFFFF;
        if (target < CAPB) lout[target] = v;
        else {
            srcs[r0 + target] = (unsigned short)v.x;
            se12[r0 + target] = (unsigned)v.y;
            se34[r0 + target] = (unsigned)v.z;
            se5[r0 + target]  = (unsigned short)v.w;
        }
    }
    __syncthreads();
    int m = min(cnt, CAPB);
    for (int k = tid; k < m; k += 1024){
        int4 v = lout[k];
        srcs[r0 + k] = (unsigned short)v.x;
        se12[r0 + k] = (unsigned)v.y;
        se34[r0 + k] = (unsigned)v.z;
        se5[r0 + k]  = (unsigned short)v.w;
    }
}

// ---------------- node transform: h = in @ W (bf16x2 packed out); s_src/s_dst fused ----
template<int OUTC>
__global__ void transform_kernel(const float* __restrict__ in, const float* __restrict__ W,
                                 const float* __restrict__ asrc, const float* __restrict__ adst,
                                 unsigned* __restrict__ hout2, float* __restrict__ ssrc,
                                 float* __restrict__ sdst, int nN){
    constexpr int R = 256/OUTC;
    __shared__ float Ws[64*OUTC];
    __shared__ float ins[R*64];
    int tid = threadIdx.x;
    for (int i = tid; i < 64*OUTC; i += 256) Ws[i] = W[i];
    int base = blockIdx.x * R;
    for (int i = tid; i < R*64; i += 256){
        int n = base + i/64;
        ins[i] = (n < nN) ? in[(size_t)n*64 + (i & 63)] : 0.f;
    }
    __syncthreads();
    int r = tid / OUTC, c = tid % OUTC;
    int n = base + r;
    float acc = 0.f;
    #pragma unroll
    for (int d = 0; d < 64; ++d) acc += ins[r*64 + d] * Ws[d*OUTC + c];
    float ps = acc * asrc[c];
    float pd = acc * adst[c];
    #pragma unroll
    for (int m = 1; m <= 16; m <<= 1){ ps += __shfl_xor(ps, m); pd += __shfl_xor(pd, m); }
    float accN = __shfl_xor(acc, 1);   // neighbor channel (lane parity == c parity)
    if (n < nN){
        if ((c & 1) == 0){
            unsigned pk = rne_bf16(acc) | (rne_bf16(accN) << 16);
            hout2[(size_t)n*(OUTC/2) + (c >> 1)] = pk;
        }
        constexpr int HEADS = OUTC/32;
        if ((c & 31) == 0){
            int h = c >> 5;
            ssrc[n*HEADS + h] = ps;
            sdst[n*HEADS + h] = pd;
        }
    }
}

// ---------------- per-dst aggregation: 4 ch/lane, EPI edges/iter, 2 shfl/edge ----------
// No max-subtraction (logits ~N(0,3), exp safe in fp32; softmax shift-invariant).
template<int OUTC>
__global__ void agg_kernel(const int* __restrict__ rowptr, const unsigned short* __restrict__ srcs,
                           const unsigned* __restrict__ sePa, const unsigned short* __restrict__ sePb,
                           const float* __restrict__ ssrc, const float* __restrict__ sdst,
                           const unsigned* __restrict__ hbuf2, const float* __restrict__ bias,
                           float* __restrict__ outbuf, int nN){
    constexpr int HEADS = OUTC/32;
    constexpr int HALF  = OUTC/4;       // lanes per edge-subgroup (4 channels each)
    constexpr int EPI   = 64/HALF;      // edges per inner iteration
    int wid = threadIdx.x >> 6;
    int lane = threadIdx.x & 63;
    int n = blockIdx.x*4 + wid;
    if (n >= nN) return;
    int row_start = rowptr[n], row_end = rowptr[n+1];
    int degn = row_end - row_start;
    float sd0 = sdst[n*HEADS + 0];
    float sd1 = (HEADS == 2) ? sdst[n*HEADS + 1] : 0.f;

    int sub = lane / HALF;
    int lc  = lane & (HALF - 1);        // channels 4lc .. 4lc+3
    int h   = (HEADS == 2) ? ((4*lc) >> 5) : 0;

    float acc0=0.f, acc1=0.f, acc2=0.f, acc3=0.f, den=0.f;
    float ssp0=0.f, ssp1=0.f;
    const uint2* hb2 = (const uint2*)hbuf2;

    for (int p0 = row_start; p0 < row_end; p0 += 64){
        int myp = p0 + lane;
        int srcreg = 0; unsigned wpk = 0; float w0s = 0.f;
        if (myp < row_end){
            srcreg = srcs[myp];
            if (HEADS == 2){
                unsigned pk = sePa[myp];
                float e0 = __uint_as_float(pk << 16);
                float e1 = __uint_as_float(pk & 0xFFFF0000u);
                ssp0 += e0; ssp1 += e1;
                float2 sv = ((const float2*)ssrc)[srcreg];
                float w0 = __expf(leaky(sv.x + sd0 + e0));
                float w1 = __expf(leaky(sv.y + sd1 + e1));
                wpk = rne_bf16(w0) | (rne_bf16(w1) << 16);
            } else {
                float e0 = __uint_as_float(((unsigned)sePb[myp]) << 16);
                ssp0 += e0;
                w0s = __expf(leaky(ssrc[srcreg] + sd0 + e0));
            }
        }
        int cnt = min(64, row_end - p0);
        for (int q = sub; q < cnt; q += EPI){
            int sj = __shfl(srcreg, q);
            float wj;
            if (HEADS == 2){
                unsigned wq = __shfl(wpk, q);
                wj = h ? __uint_as_float(wq & 0xFFFF0000u) : __uint_as_float(wq << 16);
            } else {
                wj = __shfl(w0s, q);
            }
            den += wj;
            uint2 hv = hb2[(size_t)sj*(OUTC/4) + lc];
            acc0 += wj * __uint_as_float(hv.x << 16);
            acc1 += wj * __uint_as_float(hv.x & 0xFFFF0000u);
            acc2 += wj * __uint_as_float(hv.y << 16);
            acc3 += wj * __uint_as_float(hv.y & 0xFFFF0000u);
        }
    }

    // reduce acc/den across edge-subgroups; ssp across full wave
    #pragma unroll
    for (int m = HALF; m < 64; m <<= 1){
        acc0 += __shfl_xor(acc0, m);
        acc1 += __shfl_xor(acc1, m);
        acc2 += __shfl_xor(acc2, m);
        acc3 += __shfl_xor(acc3, m);
        den  += __shfl_xor(den, m);
    }
    #pragma unroll
    for (int m = 1; m < 64; m <<= 1){
        ssp0 += __shfl_xor(ssp0, m);
        if (HEADS == 2) ssp1 += __shfl_xor(ssp1, m);
    }

    float invdeg = 1.f / (float)max(degn, 1);
    float srh = ssrc[n*HEADS + h];
    float sdh = h ? sd1 : sd0;
    float ssh = h ? ssp1 : ssp0;
    float wself = __expf(leaky(srh + sdh + ssh*invdeg));
    uint2 hv = hb2[(size_t)n*(OUTC/4) + lc];
    acc0 += wself * __uint_as_float(hv.x << 16);
    acc1 += wself * __uint_as_float(hv.x & 0xFFFF0000u);
    acc2 += wself * __uint_as_float(hv.y << 16);
    acc3 += wself * __uint_as_float(hv.y & 0xFFFF0000u);
    den += wself;

    if (lane < HALF){
        float inv = 1.f / (den + 1e-16f);
        float4 o;
        o.x = fmaxf(acc0*inv + bias[4*lc+0], 0.f);
        o.y = fmaxf(acc1*inv + bias[4*lc+1], 0.f);
        o.z = fmaxf(acc2*inv + bias[4*lc+2], 0.f);
        o.w = fmaxf(acc3*inv + bias[4*lc+3], 0.f);
        ((float4*)outbuf)[(size_t)n*(OUTC/4) + lc] = o;
    }
}

// ---------------- pooling + head ----------------
__global__ void pool_kernel(const float* __restrict__ h3, const int* __restrict__ batch,
                            float* __restrict__ pool, float* __restrict__ cnt, int nN){
    __shared__ float accs[GG*32];
    __shared__ float acccnt[GG];
    int tid = threadIdx.x;
    for (int i = tid; i < GG*32; i += 256) accs[i] = 0.f;
    if (tid < GG) acccnt[tid] = 0.f;
    __syncthreads();
    int r = tid >> 5, c = tid & 31;
    int base = blockIdx.x * 512;
    int end = min(base + 512, nN);
    for (int n = base + r; n < end; n += 8){
        int g = batch[n];
        atomicAdd(&accs[g*32 + c], h3[(size_t)n*32 + c]);
        if (c == 0) atomicAdd(&acccnt[g], 1.f);
    }
    __syncthreads();
    for (int i = tid; i < GG*32; i += 256) atomicAdd(&pool[i], accs[i]);
    if (tid < GG) atomicAdd(&cnt[tid], acccnt[tid]);
}

__global__ void final_kernel(const float* __restrict__ pool, const float* __restrict__ cnt,
                             const float* __restrict__ Wf, const float* __restrict__ bf,
                             float* __restrict__ out){
    int g = threadIdx.x;
    if (g >= GG) return;
    float ic = 1.f / fmaxf(cnt[g], 1.f);
    float lg[NCLS];
    #pragma unroll
    for (int k = 0; k < NCLS; ++k) lg[k] = bf[k];
    for (int c = 0; c < 32; ++c){
        float v = pool[g*32 + c] * ic;
        #pragma unroll
        for (int k = 0; k < NCLS; ++k) lg[k] += v * Wf[c*NCLS + k];
    }
    float mx = lg[0];
    #pragma unroll
    for (int k = 1; k < NCLS; ++k) mx = fmaxf(mx, lg[k]);
    float sum = 0.f, ex[NCLS];
    #pragma unroll
    for (int k = 0; k < NCLS; ++k){ ex[k] = expf(lg[k] - mx); sum += ex[k]; }
    #pragma unroll
    for (int k = 0; k < NCLS; ++k) out[g*NCLS + k] = ex[k]/sum;
}

extern "C" void kernel_launch(void* const* d_in, const int* in_sizes, int n_in,
                              void* d_out, int out_size, void* d_ws, size_t ws_size,
                              hipStream_t stream){
    const float* x     = (const float*)d_in[0];
    const int*   eidx  = (const int*)d_in[1];
    const float* eattr = (const float*)d_in[2];
    const int*   batch = (const int*)d_in[3];
    const float* W1 = (const float*)d_in[4];  const float* asrc1 = (const float*)d_in[5];
    const float* adst1 = (const float*)d_in[6]; const float* We1 = (const float*)d_in[7];
    const float* ae1 = (const float*)d_in[8];  const float* b1 = (const float*)d_in[9];
    const float* W2 = (const float*)d_in[10]; const float* asrc2 = (const float*)d_in[11];
    const float* adst2 = (const float*)d_in[12]; const float* We2 = (const float*)d_in[13];
    const float* ae2 = (const float*)d_in[14]; const float* b2 = (const float*)d_in[15];
    const float* W3 = (const float*)d_in[16]; const float* asrc3 = (const float*)d_in[17];
    const float* adst3 = (const float*)d_in[18]; const float* We3 = (const float*)d_in[19];
    const float* ae3 = (const float*)d_in[20]; const float* b3 = (const float*)d_in[21];
    const float* Wf = (const float*)d_in[22]; const float* bf = (const float*)d_in[23];
    float* out = (float*)d_out;

    char* ws = (char*)d_ws;
    int*   deg    = (int*)(ws + OFF_DEG);
    int*   rowptr = (int*)(ws + OFF_ROWPTR);
    int*   curs   = (int*)(ws + OFF_CURSOR);
    unsigned short* srcs = (unsigned short*)(ws + OFF_SRCS);
    unsigned* se12 = (unsigned*)(ws + OFF_SE12);
    unsigned* se34 = (unsigned*)(ws + OFF_SE34);
    unsigned short* se5 = (unsigned short*)(ws + OFF_SE5);
    float* ssrc   = (float*)(ws + OFF_SSRC);
    float* sdst   = (float*)(ws + OFF_SDST);
    int4*  staging = (int4*)(ws + OFF_STAG);
    unsigned* bufH = (unsigned*)(ws + OFF_BUFH);
    float* bufO   = (float*)(ws + OFF_BUFO);
    float* weff   = (float*)(ws + OFF_WEFF);
    float* pool   = (float*)(ws + OFF_POOL);
    float* cnt    = pool + GG*32;

    int* bincursor = curs;
    int* bsum      = curs + 512;
    int* boff      = curs + 1024;

    const int* srcA = eidx;
    const int* dstA = eidx + EE;

    hipMemsetAsync(pool, 0, (GG*32 + GG)*4, stream);

    // CSR build with fused edge-score computation
    weff_kernel<<<1, 128, 0, stream>>>(We1, ae1, We2, ae2, We3, ae3, weff);
    binit_kernel<<<(NBIN+255)/256, 256, 0, stream>>>(bincursor);
    binA_kernel<<<(EE + 8191)/8192, 1024, 0, stream>>>(srcA, dstA, eattr, weff, bincursor, staging, EE);
    hist_kernel<<<NBIN, 256, 0, stream>>>(staging, bincursor, deg, NN);
    int sgrid = (NN + 1023)/1024;  // 49
    bsum_kernel<<<sgrid, 1024, 0, stream>>>(deg, bsum, NN);
    bscan_kernel<<<1, 64, 0, stream>>>(bsum, boff, rowptr, sgrid, NN);
    wptr_kernel<<<sgrid, 1024, 0, stream>>>(deg, boff, rowptr, NN);
    binB_kernel<<<NBIN, 1024, 0, stream>>>(rowptr, staging, srcs, se12, se34, se5, NN);

    int ngrid4 = (NN + 3)/4;
    int ngrid8 = (NN + 7)/8;
    // layer 1
    transform_kernel<64><<<ngrid4, 256, 0, stream>>>(x, W1, asrc1, adst1, bufH, ssrc, sdst, NN);
    agg_kernel<64><<<ngrid4, 256, 0, stream>>>(rowptr, srcs, se12, nullptr,
                                               ssrc, sdst, bufH, b1, bufO, NN);
    // layer 2
    transform_kernel<64><<<ngrid4, 256, 0, stream>>>(bufO, W2, asrc2, adst2, bufH, ssrc, sdst, NN);
    agg_kernel<64><<<ngrid4, 256, 0, stream>>>(rowptr, srcs, se34, nullptr,
                                               ssrc, sdst, bufH, b2, bufO, NN);
    // layer 3 (1 head, 32 out, concat=False -> mean over 1 head = identity)
    transform_kernel<32><<<ngrid8, 256, 0, stream>>>(bufO, W3, asrc3, adst3, bufH, ssrc, sdst, NN);
    agg_kernel<32><<<ngrid4, 256, 0, stream>>>(rowptr, srcs, nullptr, se5,
                                               ssrc, sdst, bufH, b3, bufO, NN);
    // pool + ffn + softmax
    pool_kernel<<<(NN + 511)/512, 256, 0, stream>>>(bufO, batch, pool, cnt, NN);
    final_kernel<<<1, 64, 0, stream>>>(pool, cnt, Wf, bf, out);
}